// Round 4
// baseline (555.347 us; speedup 1.0000x reference)
//
#include <hip/hip_runtime.h>
#include <math.h>

#define THREADS 256
#define NPB 2048          // nodes per bin
#define SHIFT 11
#define MASK 2047
#define MAX_BINS 64
#define CAPE 70016        // per-bin edge capacity (mean 65.3k, +18 sigma)
#define BIN_BLOCKS 1024
#define K1 2              // chunks per (bin,quarter) in agg1
#define K2 5              // chunks per bin in agg2

// ============================ v4: binned pipeline ============================

// --- per-block LDS counting sort of edges into 49 target-bins ----------------
__global__ void __launch_bounds__(256) k_bin(const int* __restrict__ row,
                                             const int* __restrict__ col,
                                             int e, int* __restrict__ binCnt,
                                             int* __restrict__ binned) {
    __shared__ int hist[MAX_BINS];
    __shared__ int lofs[MAX_BINS];
    __shared__ int baseg[MAX_BINS];
    __shared__ int cur[MAX_BINS];
    extern __shared__ int sortbuf[];
    int per = (e + gridDim.x - 1) / gridDim.x;
    int e0 = blockIdx.x * per;
    int e1 = min(e0 + per, e);
    if (e1 <= e0) return;
    for (int t = threadIdx.x; t < MAX_BINS; t += 256) { hist[t] = 0; cur[t] = 0; }
    __syncthreads();
    for (int i = e0 + threadIdx.x; i < e1; i += 256)
        atomicAdd(&hist[col[i] >> SHIFT], 1);
    __syncthreads();
    if (threadIdx.x < MAX_BINS) {
        int h = hist[threadIdx.x];
        baseg[threadIdx.x] = (h > 0) ? atomicAdd(&binCnt[threadIdx.x], h) : 0;
    }
    if (threadIdx.x == 0) {
        int s = 0;
        for (int b = 0; b < MAX_BINS; b++) { lofs[b] = s; s += hist[b]; }
    }
    __syncthreads();
    for (int i = e0 + threadIdx.x; i < e1; i += 256) {
        int c = col[i];
        int b = c >> SHIFT;
        int slot = lofs[b] + atomicAdd(&cur[b], 1);
        sortbuf[slot] = (row[i] << SHIFT) | (c & MASK);
    }
    __syncthreads();
    for (int b = 0; b < MAX_BINS; b++) {
        int h = hist[b];
        if (h == 0) continue;
        int gb = b * CAPE + baseg[b];
        int lb = lofs[b];
        int lim = (b + 1) * CAPE;
        for (int i = threadIdx.x; i < h; i += 256) {
            int dst = gb + i;
            if (dst < lim) binned[dst] = sortbuf[lb + i];  // overflow guard (P~0)
        }
    }
}

// --- per-bin degree count -> dinv (LDS atomics only) -------------------------
__global__ void __launch_bounds__(512) k_bindeg(const int* __restrict__ binned,
                                                const int* __restrict__ binCnt,
                                                int n, float* __restrict__ dinv) {
    __shared__ int cnt[NPB];
    int b = blockIdx.x;
    for (int t = threadIdx.x; t < NPB; t += 512) cnt[t] = 0;
    __syncthreads();
    int m = min(binCnt[b], CAPE);
    const int* eb = binned + b * CAPE;
    for (int i = threadIdx.x; i < m; i += 512)
        atomicAdd(&cnt[eb[i] & MASK], 1);
    __syncthreads();
    int base = b * NPB;
    for (int t = threadIdx.x; t < NPB; t += 512) {
        int node = base + t;
        if (node < n) dinv[node] = rsqrtf((float)(cnt[t] + 1));
    }
}

// --- z1[i] = dinv[i] * (x[i] @ W1), LDS-staged x (round-3 validated) ---------
__global__ void __launch_bounds__(256) k_xform1(const float* __restrict__ x,
                                                const float* __restrict__ W1,
                                                const float* __restrict__ dinv,
                                                float* __restrict__ z1, int n) {
    __shared__ float sW[25 * 16];
    __shared__ float tile[4][64 * 25];
    int w = threadIdx.x >> 6, lane = threadIdx.x & 63;
    for (int t = threadIdx.x; t < 25 * 16; t += 256) sW[t] = W1[t];
    long blockRow = (long)blockIdx.x * 256;
    long waveRow = blockRow + w * 64;
    const float* src = x + waveRow * 25;
    long rem = (long)n * 25 - waveRow * 25;
#pragma unroll
    for (int k = 0; k < 25; k++) {
        int idx = k * 64 + lane;
        tile[w][idx] = (idx < rem) ? src[idx] : 0.f;
    }
    __syncthreads();
    long node = blockRow + threadIdx.x;
    if (node >= n) return;
    float xi[25];
#pragma unroll
    for (int k = 0; k < 25; k++) xi[k] = tile[w][lane * 25 + k];
    float di = dinv[node];
    float s[16];
#pragma unroll
    for (int c = 0; c < 16; c++) {
        float a = 0.f;
#pragma unroll
        for (int k = 0; k < 25; k++) a = fmaf(xi[k], sW[k * 16 + c], a);
        s[c] = a * di;
    }
    float4* o = (float4*)(z1 + node * 16);
#pragma unroll
    for (int q = 0; q < 4; q++) o[q] = make_float4(s[q * 4], s[q * 4 + 1], s[q * 4 + 2], s[q * 4 + 3]);
}

// --- layer-1 aggregation: bin x quarter x chunk, LDS f32 accumulator ---------
__global__ void __launch_bounds__(256) k_agg1(const int* __restrict__ binned,
                                              const int* __restrict__ binCnt,
                                              const float* __restrict__ z1,
                                              float* __restrict__ P1, int NP) {
    __shared__ float acc[512 * 17];  // stride 17: bank-conflict-free
    int b = blockIdx.x / (4 * K1);
    int r = blockIdx.x % (4 * K1);
    int quarter = r / K1;
    int k = r % K1;
    for (int t = threadIdx.x; t < 512 * 17; t += 256) acc[t] = 0.f;
    __syncthreads();
    int m = min(binCnt[b], CAPE);
    int c0 = (int)((long)m * k / K1), c1 = (int)((long)m * (k + 1) / K1);
    const int* eb = binned + b * CAPE;
    for (int i = c0 + threadIdx.x; i < c1; i += 256) {
        int v = eb[i];
        int c11 = v & MASK;
        if ((c11 >> 9) != quarter) continue;
        int s = v >> SHIFT;
        int loc = (c11 & 511) * 17;
        const float4* zp = (const float4*)(z1 + (size_t)s * 16);
        float4 a = zp[0], bq = zp[1], cq = zp[2], dq = zp[3];
        atomicAdd(&acc[loc + 0],  a.x);  atomicAdd(&acc[loc + 1],  a.y);
        atomicAdd(&acc[loc + 2],  a.z);  atomicAdd(&acc[loc + 3],  a.w);
        atomicAdd(&acc[loc + 4],  bq.x); atomicAdd(&acc[loc + 5],  bq.y);
        atomicAdd(&acc[loc + 6],  bq.z); atomicAdd(&acc[loc + 7],  bq.w);
        atomicAdd(&acc[loc + 8],  cq.x); atomicAdd(&acc[loc + 9],  cq.y);
        atomicAdd(&acc[loc + 10], cq.z); atomicAdd(&acc[loc + 11], cq.w);
        atomicAdd(&acc[loc + 12], dq.x); atomicAdd(&acc[loc + 13], dq.y);
        atomicAdd(&acc[loc + 14], dq.z); atomicAdd(&acc[loc + 15], dq.w);
    }
    __syncthreads();
    float* dst = P1 + ((size_t)k * NP + (size_t)b * NPB + quarter * 512) * 16;
    for (int t = threadIdx.x; t < 512 * 16; t += 256)
        dst[t] = acc[(t >> 4) * 17 + (t & 15)];
}

// --- merge partials + bias/relu + @W2 (16 lanes per node) --------------------
__global__ void k_fin1(const float* __restrict__ z1, const float* __restrict__ P1,
                       const float* __restrict__ dinv, const float* __restrict__ b1,
                       const float* __restrict__ W2, float* __restrict__ z2,
                       int n, int NP) {
    int g = threadIdx.x >> 4, c = threadIdx.x & 15;
    int node = blockIdx.x * 16 + g;
    if (node >= n) return;
    float s = z1[(size_t)node * 16 + c];
#pragma unroll
    for (int k = 0; k < K1; k++) s += P1[((size_t)k * NP + node) * 16 + c];
    float di = dinv[node];
    float h = fmaxf(fmaf(di, s, b1[c]), 0.f);
    float p0 = h * W2[c * 2 + 0];
    float p1 = h * W2[c * 2 + 1];
#pragma unroll
    for (int m = 1; m < 16; m <<= 1) {
        p0 += __shfl_xor(p0, m, 16);
        p1 += __shfl_xor(p1, m, 16);
    }
    if (c == 0) {
        z2[(size_t)node * 2 + 0] = di * p0;
        z2[(size_t)node * 2 + 1] = di * p1;
    }
}

// --- layer-2 aggregation: bin x chunk, LDS accumulator -----------------------
__global__ void __launch_bounds__(256) k_agg2(const int* __restrict__ binned,
                                              const int* __restrict__ binCnt,
                                              const float* __restrict__ z2,
                                              float* __restrict__ P2, int NP) {
    __shared__ float acc[NPB * 3];  // stride 3: conflict-free
    int b = blockIdx.x / K2, k = blockIdx.x % K2;
    for (int t = threadIdx.x; t < NPB * 3; t += 256) acc[t] = 0.f;
    __syncthreads();
    int m = min(binCnt[b], CAPE);
    int c0 = (int)((long)m * k / K2), c1 = (int)((long)m * (k + 1) / K2);
    const int* eb = binned + b * CAPE;
    for (int i = c0 + threadIdx.x; i < c1; i += 256) {
        int v = eb[i];
        int c11 = v & MASK;
        int s = v >> SHIFT;
        float2 z = ((const float2*)z2)[s];
        atomicAdd(&acc[c11 * 3 + 0], z.x);
        atomicAdd(&acc[c11 * 3 + 1], z.y);
    }
    __syncthreads();
    float* dst = P2 + ((size_t)k * NP + (size_t)b * NPB) * 2;
    for (int t = threadIdx.x; t < NPB * 2; t += 256)
        dst[t] = acc[(t >> 1) * 3 + (t & 1)];
}

// --- merge + bias + log_softmax(2) -------------------------------------------
__global__ void k_fin2(const float* __restrict__ z2, const float* __restrict__ P2,
                       const float* __restrict__ dinv, const float* __restrict__ b2,
                       float* __restrict__ out, int n, int NP) {
    int node = blockIdx.x * blockDim.x + threadIdx.x;
    if (node >= n) return;
    float2 sv = ((const float2*)z2)[node];
    float a0 = sv.x, a1 = sv.y;
#pragma unroll
    for (int k = 0; k < K2; k++) {
        float2 p = ((const float2*)P2)[(size_t)k * NP + node];
        a0 += p.x; a1 += p.y;
    }
    float di = dinv[node];
    float h0 = fmaf(di, a0, b2[0]);
    float h1 = fmaf(di, a1, b2[1]);
    float mx = fmaxf(h0, h1);
    float lse = mx + log1pf(expf(fminf(h0, h1) - mx));
    out[(size_t)node * 2 + 0] = h0 - lse;
    out[(size_t)node * 2 + 1] = h1 - lse;
}

// ===================== fallback: round-2 CSR pipeline ========================

__global__ void k_zero(int* cnt, int n) {
    int i = blockIdx.x * blockDim.x + threadIdx.x;
    if (i < n) cnt[i] = 0;
}

__global__ void k_count_pos(const int* __restrict__ col, int e,
                            int* __restrict__ cnt, int* __restrict__ pos) {
    int i = blockIdx.x * blockDim.x + threadIdx.x;
    if (i < e) pos[i] = atomicAdd(&cnt[col[i]], 1);
}

__global__ void k_scan1(const int* __restrict__ cnt, int n,
                        int* __restrict__ excl, int* __restrict__ bsum) {
    __shared__ int s[256];
    int i = blockIdx.x * 256 + threadIdx.x;
    int v = (i < n) ? cnt[i] : 0;
    s[threadIdx.x] = v;
    __syncthreads();
    for (int off = 1; off < 256; off <<= 1) {
        int t = (threadIdx.x >= off) ? s[threadIdx.x - off] : 0;
        __syncthreads();
        s[threadIdx.x] += t;
        __syncthreads();
    }
    if (i < n) excl[i] = s[threadIdx.x] - v;
    if (threadIdx.x == 255) bsum[blockIdx.x] = s[255];
}

__global__ void k_scan2(int* __restrict__ bsum, int nb) {
    __shared__ int s[1024];
    int v = (threadIdx.x < nb) ? bsum[threadIdx.x] : 0;
    s[threadIdx.x] = v;
    __syncthreads();
    for (int off = 1; off < 1024; off <<= 1) {
        int t = (threadIdx.x >= off) ? s[threadIdx.x - off] : 0;
        __syncthreads();
        s[threadIdx.x] += t;
        __syncthreads();
    }
    if (threadIdx.x < nb) bsum[threadIdx.x] = s[threadIdx.x] - v;
}

__global__ void k_scan3(int* __restrict__ excl, const int* __restrict__ boff, int n) {
    int i = blockIdx.x * 256 + threadIdx.x;
    if (i < n) excl[i] += boff[blockIdx.x];
}

__global__ void k_place(const int* __restrict__ row, const int* __restrict__ col,
                        const int* __restrict__ pos, const int* __restrict__ ptr,
                        int e, int* __restrict__ csr) {
    int i = blockIdx.x * blockDim.x + threadIdx.x;
    if (i >= e) return;
    csr[ptr[col[i]] + pos[i]] = row[i];
}

__global__ void k_dinv_from_cnt(const int* __restrict__ cnt, float* __restrict__ dinv, int n) {
    int i = blockIdx.x * blockDim.x + threadIdx.x;
    if (i < n) dinv[i] = rsqrtf((float)(cnt[i] + 1));
}

__global__ void k_gather1_fb(const int* __restrict__ ptr, const int* __restrict__ cnt,
                             const int* __restrict__ csr, const float* __restrict__ hs1,
                             const float* __restrict__ b1, const float* __restrict__ W2,
                             float* __restrict__ hs2, int n) {
    int g = threadIdx.x >> 4, c = threadIdx.x & 15;
    int node = blockIdx.x * 16 + g;
    if (node >= n) return;
    int beg = ptr[node], d = cnt[node];
    float acc = hs1[(size_t)node * 16 + c];
    for (int e = 0; e < d; e++) acc += hs1[(size_t)csr[beg + e] * 16 + c];
    float di = rsqrtf((float)(d + 1));
    float h = fmaxf(fmaf(di, acc, b1[c]), 0.f);
    float p0 = h * W2[c * 2 + 0];
    float p1 = h * W2[c * 2 + 1];
#pragma unroll
    for (int m = 1; m < 16; m <<= 1) {
        p0 += __shfl_xor(p0, m, 16);
        p1 += __shfl_xor(p1, m, 16);
    }
    if (c == 0) {
        hs2[(size_t)node * 2 + 0] = di * p0;
        hs2[(size_t)node * 2 + 1] = di * p1;
    }
}

__global__ void k_gather2_fb(const int* __restrict__ ptr, const int* __restrict__ cnt,
                             const int* __restrict__ csr, const float* __restrict__ hs2,
                             const float* __restrict__ b2, float* __restrict__ out, int n) {
    int node = blockIdx.x * blockDim.x + threadIdx.x;
    if (node >= n) return;
    int beg = ptr[node], d = cnt[node];
    float2 self = ((const float2*)hs2)[node];
    float a0 = self.x, a1 = self.y;
    for (int e = 0; e < d; e++) {
        float2 v = ((const float2*)hs2)[csr[beg + e]];
        a0 += v.x; a1 += v.y;
    }
    float di = rsqrtf((float)(d + 1));
    float h0 = fmaf(di, a0, b2[0]);
    float h1 = fmaf(di, a1, b2[1]);
    float m = fmaxf(h0, h1);
    float lse = m + log1pf(expf(fminf(h0, h1) - m));
    out[(size_t)node * 2 + 0] = h0 - lse;
    out[(size_t)node * 2 + 1] = h1 - lse;
}

// ============================== host launcher ================================

extern "C" void kernel_launch(void* const* d_in, const int* in_sizes, int n_in,
                              void* d_out, int out_size, void* d_ws, size_t ws_size,
                              hipStream_t stream) {
    const float* x  = (const float*)d_in[0];
    const int*   ei = (const int*)d_in[1];
    const float* W1 = (const float*)d_in[2];
    const float* b1 = (const float*)d_in[3];
    const float* W2 = (const float*)d_in[4];
    const float* b2 = (const float*)d_in[5];
    float* out = (float*)d_out;

    const int N = in_sizes[0] / 25;
    const int E = in_sizes[1] / 2;
    const int* row = ei;
    const int* col = ei + E;

    const int nbins = (N + NPB - 1) / NPB;
    const int NP = nbins * NPB;
    const int gN = (N + THREADS - 1) / THREADS;
    const int gE = (E + THREADS - 1) / THREADS;

    // v4 workspace layout (256-B aligned slices)
    size_t off = 0;
    auto take = [&](size_t bytes) { size_t o = off; off = (off + bytes + 255) & ~(size_t)255; return o; };
    size_t o_binCnt = take(MAX_BINS * sizeof(int));
    size_t o_binned = take((size_t)nbins * CAPE * sizeof(int));
    size_t o_dinv   = take((size_t)N * sizeof(float));
    size_t o_z1     = take((size_t)NP * 16 * sizeof(float));
    size_t o_P1     = take((size_t)K1 * NP * 16 * sizeof(float));
    size_t o_z2     = take((size_t)NP * 2 * sizeof(float));
    size_t o_P2     = take((size_t)K2 * NP * 2 * sizeof(float));
    size_t need_v4 = off;

    bool use_v4 = (nbins <= MAX_BINS) && (ws_size >= need_v4) && (N < (1 << 17));

    if (use_v4) {
        char* wsb = (char*)d_ws;
        int*   binCnt = (int*)(wsb + o_binCnt);
        int*   binned = (int*)(wsb + o_binned);
        float* dinv   = (float*)(wsb + o_dinv);
        float* z1     = (float*)(wsb + o_z1);
        float* P1     = (float*)(wsb + o_P1);
        float* z2     = (float*)(wsb + o_z2);
        float* P2     = (float*)(wsb + o_P2);

        const int per = (E + BIN_BLOCKS - 1) / BIN_BLOCKS;
        hipMemsetAsync(binCnt, 0, MAX_BINS * sizeof(int), stream);
        k_bin<<<BIN_BLOCKS, 256, per * sizeof(int), stream>>>(row, col, E, binCnt, binned);
        k_bindeg<<<nbins, 512, 0, stream>>>(binned, binCnt, N, dinv);
        k_xform1<<<gN, 256, 0, stream>>>(x, W1, dinv, z1, N);
        k_agg1<<<nbins * 4 * K1, 256, 0, stream>>>(binned, binCnt, z1, P1, NP);
        k_fin1<<<(N + 15) / 16, 256, 0, stream>>>(z1, P1, dinv, b1, W2, z2, N, NP);
        k_agg2<<<nbins * K2, 256, 0, stream>>>(binned, binCnt, z2, P2, NP);
        k_fin2<<<gN, THREADS, 0, stream>>>(z2, P2, dinv, b2, out, N, NP);
    } else {
        char* w = (char*)d_ws;
        int*   cnt  = (int*)w;    w += (size_t)N * sizeof(int);
        int*   ptr  = (int*)w;    w += (size_t)N * sizeof(int);
        int*   pos  = (int*)w;    w += (size_t)E * sizeof(int);
        int*   csr  = (int*)w;    w += (size_t)E * sizeof(int);
        int*   bsum = (int*)w;    w += (size_t)1024 * sizeof(int);
        float* dinv = (float*)w;  w += (size_t)N * sizeof(float);
        float* hs1  = (float*)w;  w += (size_t)N * 16 * sizeof(float);
        float* hs2  = (float*)w;  w += (size_t)N * 2 * sizeof(float);
        const int NB = (N + 255) / 256;

        k_zero<<<gN, THREADS, 0, stream>>>(cnt, N);
        k_count_pos<<<gE, THREADS, 0, stream>>>(col, E, cnt, pos);
        k_scan1<<<NB, 256, 0, stream>>>(cnt, N, ptr, bsum);
        k_scan2<<<1, 1024, 0, stream>>>(bsum, NB);
        k_scan3<<<NB, 256, 0, stream>>>(ptr, bsum, N);
        k_place<<<gE, THREADS, 0, stream>>>(row, col, pos, ptr, E, csr);
        k_dinv_from_cnt<<<gN, THREADS, 0, stream>>>(cnt, dinv, N);
        k_xform1<<<gN, 256, 0, stream>>>(x, W1, dinv, hs1, N);
        k_gather1_fb<<<(N + 15) / 16, 256, 0, stream>>>(ptr, cnt, csr, hs1, b1, W2, hs2, N);
        k_gather2_fb<<<gN, THREADS, 0, stream>>>(ptr, cnt, csr, hs2, b2, out, N);
    }
}

// Round 5
// 341.597 us; speedup vs baseline: 1.6257x; 1.6257x over previous
//
#include <hip/hip_runtime.h>
#include <math.h>

#define THREADS 256
#define NPB 1024          // nodes per bin
#define SHIFT 10
#define MASK 1023
#define MAX_BINS 128
#define CAPE 36864        // per-bin edge capacity (mean 32.6k, ~+23 sigma)
#define BIN_BLOCKS 1024

// ===================== stage 1: bin edges by target>>10 ======================
// Per-block LDS counting sort into up to 128 bins, coalesced global flush.
// Proven cheap in round 4 (never appeared in top-5 dispatches).

__global__ void __launch_bounds__(256) k_bin(const int* __restrict__ row,
                                             const int* __restrict__ col,
                                             int e, int* __restrict__ binCnt,
                                             int* __restrict__ binned) {
    __shared__ int hist[MAX_BINS];
    __shared__ int lofs[MAX_BINS];
    __shared__ int baseg[MAX_BINS];
    __shared__ int cur[MAX_BINS];
    extern __shared__ int sortbuf[];
    int per = (e + gridDim.x - 1) / gridDim.x;
    int e0 = blockIdx.x * per;
    int e1 = min(e0 + per, e);
    if (e1 <= e0) return;
    for (int t = threadIdx.x; t < MAX_BINS; t += 256) { hist[t] = 0; cur[t] = 0; }
    __syncthreads();
    for (int i = e0 + threadIdx.x; i < e1; i += 256)
        atomicAdd(&hist[col[i] >> SHIFT], 1);
    __syncthreads();
    if (threadIdx.x < MAX_BINS) {
        int h = hist[threadIdx.x];
        baseg[threadIdx.x] = (h > 0) ? atomicAdd(&binCnt[threadIdx.x], h) : 0;
    }
    if (threadIdx.x == 0) {
        int s = 0;
        for (int b = 0; b < MAX_BINS; b++) { lofs[b] = s; s += hist[b]; }
    }
    __syncthreads();
    for (int i = e0 + threadIdx.x; i < e1; i += 256) {
        int c = col[i];
        int b = c >> SHIFT;
        int slot = lofs[b] + atomicAdd(&cur[b], 1);
        sortbuf[slot] = (row[i] << SHIFT) | (c & MASK);  // row < 2^21 fits
    }
    __syncthreads();
    for (int b = 0; b < MAX_BINS; b++) {
        int h = hist[b];
        if (h == 0) continue;
        int gb = b * CAPE + baseg[b];
        int lb = lofs[b];
        int lim = (b + 1) * CAPE;
        for (int i = threadIdx.x; i < h; i += 256) {
            int dst = gb + i;
            if (dst < lim) binned[dst] = sortbuf[lb + i];  // overflow guard (P~0)
        }
    }
}

// ======= stage 2: per-bin counting sort -> CSR + deg + ptr + dinv ============
// Scattered csr stores confined to a <=144KB window per block -> L2 writeback
// absorbs them (full lines evict), no global atomics, no write-through.

__global__ void __launch_bounds__(1024) k_sort(const int* __restrict__ binned,
                                               const int* __restrict__ binCnt,
                                               int* __restrict__ csr,
                                               int* __restrict__ gptr,
                                               int* __restrict__ gcnt,
                                               float* __restrict__ dinv, int n) {
    __shared__ int cnt[NPB];
    __shared__ int scn[NPB];
    int b = blockIdx.x;
    int t = threadIdx.x;
    cnt[t] = 0;
    __syncthreads();
    int m = min(binCnt[b], CAPE);
    const int* eb = binned + b * CAPE;
    for (int i = t; i < m; i += 1024)
        atomicAdd(&cnt[eb[i] & MASK], 1);
    __syncthreads();
    int v = cnt[t];
    scn[t] = v;
    __syncthreads();
    // Hillis-Steele inclusive scan over 1024
    for (int off = 1; off < NPB; off <<= 1) {
        int a = (t >= off) ? scn[t - off] : 0;
        __syncthreads();
        scn[t] += a;
        __syncthreads();
    }
    int excl = scn[t] - v;
    int node = b * NPB + t;
    if (node < n) {
        gptr[node] = b * CAPE + excl;
        gcnt[node] = v;
        dinv[node] = rsqrtf((float)(v + 1));
    }
    cnt[t] = excl;  // reuse as cursor
    __syncthreads();
    for (int i = t; i < m; i += 1024) {
        int e = eb[i];
        int slot = atomicAdd(&cnt[e & MASK], 1);
        csr[b * CAPE + slot] = e >> SHIFT;
    }
}

// --- z1[i] = dinv[i] * (x[i] @ W1), LDS-staged x (validated) -----------------
__global__ void __launch_bounds__(256) k_xform1(const float* __restrict__ x,
                                                const float* __restrict__ W1,
                                                const float* __restrict__ dinv,
                                                float* __restrict__ z1, int n) {
    __shared__ float sW[25 * 16];
    __shared__ float tile[4][64 * 25];
    int w = threadIdx.x >> 6, lane = threadIdx.x & 63;
    for (int t = threadIdx.x; t < 25 * 16; t += 256) sW[t] = W1[t];
    long blockRow = (long)blockIdx.x * 256;
    long waveRow = blockRow + w * 64;
    const float* src = x + waveRow * 25;
    long rem = (long)n * 25 - waveRow * 25;
#pragma unroll
    for (int k = 0; k < 25; k++) {
        int idx = k * 64 + lane;
        tile[w][idx] = (idx < rem) ? src[idx] : 0.f;
    }
    __syncthreads();
    long node = blockRow + threadIdx.x;
    if (node >= n) return;
    float xi[25];
#pragma unroll
    for (int k = 0; k < 25; k++) xi[k] = tile[w][lane * 25 + k];
    float di = dinv[node];
    float s[16];
#pragma unroll
    for (int c = 0; c < 16; c++) {
        float a = 0.f;
#pragma unroll
        for (int k = 0; k < 25; k++) a = fmaf(xi[k], sW[k * 16 + c], a);
        s[c] = a * di;
    }
    float4* o = (float4*)(z1 + node * 16);
#pragma unroll
    for (int q = 0; q < 4; q++) o[q] = make_float4(s[q * 4], s[q * 4 + 1], s[q * 4 + 2], s[q * 4 + 3]);
}

// --- gather layer 1 + bias/relu + @W2 (16 lanes per node, 4-unrolled) --------
__global__ void k_gather1(const int* __restrict__ ptr, const int* __restrict__ cnt,
                          const int* __restrict__ csr, const float* __restrict__ z1,
                          const float* __restrict__ dinv,
                          const float* __restrict__ b1, const float* __restrict__ W2,
                          float* __restrict__ z2, int n) {
    int g = threadIdx.x >> 4;
    int c = threadIdx.x & 15;
    int node = blockIdx.x * 16 + g;
    if (node >= n) return;
    int beg = ptr[node], d = cnt[node];
    float acc = z1[(size_t)node * 16 + c];  // self loop (z1 pre-scaled by dinv)
    int e = 0;
    for (; e + 4 <= d; e += 4) {
        int s0 = csr[beg + e], s1 = csr[beg + e + 1];
        int s2 = csr[beg + e + 2], s3 = csr[beg + e + 3];
        float v0 = z1[(size_t)s0 * 16 + c];
        float v1 = z1[(size_t)s1 * 16 + c];
        float v2 = z1[(size_t)s2 * 16 + c];
        float v3 = z1[(size_t)s3 * 16 + c];
        acc += ((v0 + v1) + (v2 + v3));
    }
    for (; e < d; e++) acc += z1[(size_t)csr[beg + e] * 16 + c];
    float di = dinv[node];
    float h = fmaxf(fmaf(di, acc, b1[c]), 0.f);
    float p0 = h * W2[c * 2 + 0];
    float p1 = h * W2[c * 2 + 1];
#pragma unroll
    for (int m = 1; m < 16; m <<= 1) {
        p0 += __shfl_xor(p0, m, 16);
        p1 += __shfl_xor(p1, m, 16);
    }
    if (c == 0) {
        z2[(size_t)node * 2 + 0] = di * p0;
        z2[(size_t)node * 2 + 1] = di * p1;
    }
}

// --- gather layer 2 + bias + log_softmax(2) ----------------------------------
__global__ void k_gather2(const int* __restrict__ ptr, const int* __restrict__ cnt,
                          const int* __restrict__ csr, const float* __restrict__ z2,
                          const float* __restrict__ dinv,
                          const float* __restrict__ b2, float* __restrict__ out, int n) {
    int node = blockIdx.x * blockDim.x + threadIdx.x;
    if (node >= n) return;
    int beg = ptr[node], d = cnt[node];
    float2 self = ((const float2*)z2)[node];
    float a0 = self.x, a1 = self.y;
    int e = 0;
    for (; e + 4 <= d; e += 4) {
        float2 v0 = ((const float2*)z2)[csr[beg + e]];
        float2 v1 = ((const float2*)z2)[csr[beg + e + 1]];
        float2 v2 = ((const float2*)z2)[csr[beg + e + 2]];
        float2 v3 = ((const float2*)z2)[csr[beg + e + 3]];
        a0 += ((v0.x + v1.x) + (v2.x + v3.x));
        a1 += ((v0.y + v1.y) + (v2.y + v3.y));
    }
    for (; e < d; e++) {
        float2 v = ((const float2*)z2)[csr[beg + e]];
        a0 += v.x; a1 += v.y;
    }
    float di = dinv[node];
    float h0 = fmaf(di, a0, b2[0]);
    float h1 = fmaf(di, a1, b2[1]);
    float m = fmaxf(h0, h1);
    float lse = m + log1pf(expf(fminf(h0, h1) - m));
    out[(size_t)node * 2 + 0] = h0 - lse;
    out[(size_t)node * 2 + 1] = h1 - lse;
}

// ===================== fallback: round-2 CSR pipeline (347us proven) =========

__global__ void k_zero(int* cnt, int n) {
    int i = blockIdx.x * blockDim.x + threadIdx.x;
    if (i < n) cnt[i] = 0;
}

__global__ void k_count_pos(const int* __restrict__ col, int e,
                            int* __restrict__ cnt, int* __restrict__ pos) {
    int i = blockIdx.x * blockDim.x + threadIdx.x;
    if (i < e) pos[i] = atomicAdd(&cnt[col[i]], 1);
}

__global__ void k_scan1(const int* __restrict__ cnt, int n,
                        int* __restrict__ excl, int* __restrict__ bsum) {
    __shared__ int s[256];
    int i = blockIdx.x * 256 + threadIdx.x;
    int v = (i < n) ? cnt[i] : 0;
    s[threadIdx.x] = v;
    __syncthreads();
    for (int off = 1; off < 256; off <<= 1) {
        int t = (threadIdx.x >= off) ? s[threadIdx.x - off] : 0;
        __syncthreads();
        s[threadIdx.x] += t;
        __syncthreads();
    }
    if (i < n) excl[i] = s[threadIdx.x] - v;
    if (threadIdx.x == 255) bsum[blockIdx.x] = s[255];
}

__global__ void k_scan2(int* __restrict__ bsum, int nb) {
    __shared__ int s[1024];
    int v = (threadIdx.x < nb) ? bsum[threadIdx.x] : 0;
    s[threadIdx.x] = v;
    __syncthreads();
    for (int off = 1; off < 1024; off <<= 1) {
        int t = (threadIdx.x >= off) ? s[threadIdx.x - off] : 0;
        __syncthreads();
        s[threadIdx.x] += t;
        __syncthreads();
    }
    if (threadIdx.x < nb) bsum[threadIdx.x] = s[threadIdx.x] - v;
}

__global__ void k_scan3(int* __restrict__ excl, const int* __restrict__ boff, int n) {
    int i = blockIdx.x * 256 + threadIdx.x;
    if (i < n) excl[i] += boff[blockIdx.x];
}

__global__ void k_place(const int* __restrict__ row, const int* __restrict__ col,
                        const int* __restrict__ pos, const int* __restrict__ ptr,
                        int e, int* __restrict__ csr) {
    int i = blockIdx.x * blockDim.x + threadIdx.x;
    if (i >= e) return;
    csr[ptr[col[i]] + pos[i]] = row[i];
}

__global__ void k_dinv_from_cnt(const int* __restrict__ cnt, float* __restrict__ dinv, int n) {
    int i = blockIdx.x * blockDim.x + threadIdx.x;
    if (i < n) dinv[i] = rsqrtf((float)(cnt[i] + 1));
}

// ============================== host launcher ================================

extern "C" void kernel_launch(void* const* d_in, const int* in_sizes, int n_in,
                              void* d_out, int out_size, void* d_ws, size_t ws_size,
                              hipStream_t stream) {
    const float* x  = (const float*)d_in[0];
    const int*   ei = (const int*)d_in[1];
    const float* W1 = (const float*)d_in[2];
    const float* b1 = (const float*)d_in[3];
    const float* W2 = (const float*)d_in[4];
    const float* b2 = (const float*)d_in[5];
    float* out = (float*)d_out;

    const int N = in_sizes[0] / 25;
    const int E = in_sizes[1] / 2;
    const int* row = ei;
    const int* col = ei + E;

    const int nbins = (N + NPB - 1) / NPB;
    const int gN = (N + THREADS - 1) / THREADS;
    const int gE = (E + THREADS - 1) / THREADS;

    size_t off = 0;
    auto take = [&](size_t bytes) { size_t o = off; off = (off + bytes + 255) & ~(size_t)255; return o; };
    size_t o_binCnt = take(MAX_BINS * sizeof(int));
    size_t o_binned = take((size_t)nbins * CAPE * sizeof(int));
    size_t o_csr    = take((size_t)nbins * CAPE * sizeof(int));
    size_t o_ptr    = take((size_t)N * sizeof(int));
    size_t o_cnt    = take((size_t)N * sizeof(int));
    size_t o_dinv   = take((size_t)N * sizeof(float));
    size_t o_z1     = take((size_t)N * 16 * sizeof(float));
    size_t o_z2     = take((size_t)N * 2 * sizeof(float));
    size_t need_v5 = off;

    // capacity check: mean edges/bin must be well under CAPE
    bool use_v5 = (nbins <= MAX_BINS) && (ws_size >= need_v5) &&
                  (N < (1 << 21)) && ((size_t)E / nbins < (size_t)(CAPE * 3 / 4));

    if (use_v5) {
        char* wsb = (char*)d_ws;
        int*   binCnt = (int*)(wsb + o_binCnt);
        int*   binned = (int*)(wsb + o_binned);
        int*   csr    = (int*)(wsb + o_csr);
        int*   ptr    = (int*)(wsb + o_ptr);
        int*   cnt    = (int*)(wsb + o_cnt);
        float* dinv   = (float*)(wsb + o_dinv);
        float* z1     = (float*)(wsb + o_z1);
        float* z2     = (float*)(wsb + o_z2);

        const int per = (E + BIN_BLOCKS - 1) / BIN_BLOCKS;
        hipMemsetAsync(binCnt, 0, MAX_BINS * sizeof(int), stream);
        k_bin<<<BIN_BLOCKS, 256, per * sizeof(int), stream>>>(row, col, E, binCnt, binned);
        k_sort<<<nbins, 1024, 0, stream>>>(binned, binCnt, csr, ptr, cnt, dinv, N);
        k_xform1<<<gN, 256, 0, stream>>>(x, W1, dinv, z1, N);
        k_gather1<<<(N + 15) / 16, 256, 0, stream>>>(ptr, cnt, csr, z1, dinv, b1, W2, z2, N);
        k_gather2<<<gN, THREADS, 0, stream>>>(ptr, cnt, csr, z2, dinv, b2, out, N);
    } else {
        char* w = (char*)d_ws;
        int*   cnt  = (int*)w;    w += (size_t)N * sizeof(int);
        int*   ptr  = (int*)w;    w += (size_t)N * sizeof(int);
        int*   pos  = (int*)w;    w += (size_t)E * sizeof(int);
        int*   csr  = (int*)w;    w += (size_t)E * sizeof(int);
        int*   bsum = (int*)w;    w += (size_t)1024 * sizeof(int);
        float* dinv = (float*)w;  w += (size_t)N * sizeof(float);
        float* z1   = (float*)w;  w += (size_t)N * 16 * sizeof(float);
        float* z2   = (float*)w;  w += (size_t)N * 2 * sizeof(float);
        const int NB = (N + 255) / 256;

        k_zero<<<gN, THREADS, 0, stream>>>(cnt, N);
        k_count_pos<<<gE, THREADS, 0, stream>>>(col, E, cnt, pos);
        k_scan1<<<NB, 256, 0, stream>>>(cnt, N, ptr, bsum);
        k_scan2<<<1, 1024, 0, stream>>>(bsum, NB);
        k_scan3<<<NB, 256, 0, stream>>>(ptr, bsum, N);
        k_place<<<gE, THREADS, 0, stream>>>(row, col, pos, ptr, E, csr);
        k_dinv_from_cnt<<<gN, THREADS, 0, stream>>>(cnt, dinv, N);
        k_xform1<<<gN, 256, 0, stream>>>(x, W1, dinv, z1, N);
        k_gather1<<<(N + 15) / 16, 256, 0, stream>>>(ptr, cnt, csr, z1, dinv, b1, W2, z2, N);
        k_gather2<<<gN, THREADS, 0, stream>>>(ptr, cnt, csr, z2, dinv, b2, out, N);
    }
}

// Round 6
// 250.340 us; speedup vs baseline: 2.2184x; 1.3645x over previous
//
#include <hip/hip_runtime.h>
#include <math.h>

#define THREADS 256
#define NPB 1024          // nodes per bin
#define SHIFT 10
#define MASK 1023
#define MAX_BINS 128
#define CAPE 36864        // per-bin edge capacity (mean 32.6k at E=3.2M/98 bins, +23 sigma)
#define BIN_BLOCKS 1024

// ===================== stage 1: bin edges by target>>10 ======================
// Per-block LDS counting sort into up to 128 bins, coalesced global flush.
// Proven cheap in round 4 (never appeared in top-5 dispatches).

__global__ void __launch_bounds__(256) k_bin(const int* __restrict__ row,
                                             const int* __restrict__ col,
                                             int e, int* __restrict__ binCnt,
                                             int* __restrict__ binned) {
    __shared__ int hist[MAX_BINS];
    __shared__ int lofs[MAX_BINS];
    __shared__ int baseg[MAX_BINS];
    __shared__ int cur[MAX_BINS];
    extern __shared__ int sortbuf[];
    int per = (e + gridDim.x - 1) / gridDim.x;
    int e0 = blockIdx.x * per;
    int e1 = min(e0 + per, e);
    if (e1 <= e0) return;
    for (int t = threadIdx.x; t < MAX_BINS; t += 256) { hist[t] = 0; cur[t] = 0; }
    __syncthreads();
    for (int i = e0 + threadIdx.x; i < e1; i += 256)
        atomicAdd(&hist[col[i] >> SHIFT], 1);
    __syncthreads();
    if (threadIdx.x < MAX_BINS) {
        int h = hist[threadIdx.x];
        baseg[threadIdx.x] = (h > 0) ? atomicAdd(&binCnt[threadIdx.x], h) : 0;
    }
    if (threadIdx.x == 0) {
        int s = 0;
        for (int b = 0; b < MAX_BINS; b++) { lofs[b] = s; s += hist[b]; }
    }
    __syncthreads();
    for (int i = e0 + threadIdx.x; i < e1; i += 256) {
        int c = col[i];
        int b = c >> SHIFT;
        int slot = lofs[b] + atomicAdd(&cur[b], 1);
        sortbuf[slot] = (row[i] << SHIFT) | (c & MASK);  // row < 2^21 fits
    }
    __syncthreads();
    for (int b = 0; b < MAX_BINS; b++) {
        int h = hist[b];
        if (h == 0) continue;
        int gb = b * CAPE + baseg[b];
        int lb = lofs[b];
        int lim = (b + 1) * CAPE;
        for (int i = threadIdx.x; i < h; i += 256) {
            int dst = gb + i;
            if (dst < lim) binned[dst] = sortbuf[lb + i];  // overflow guard (P~0)
        }
    }
}

// ======= stage 2: per-bin counting sort -> CSR + deg + ptr + dinv ============
// Scattered csr stores confined to a <=144KB window per block -> L2 writeback
// absorbs them, no global atomics, no per-edge write-through.

__global__ void __launch_bounds__(1024) k_sort(const int* __restrict__ binned,
                                               const int* __restrict__ binCnt,
                                               int* __restrict__ csr,
                                               int* __restrict__ gptr,
                                               int* __restrict__ gcnt,
                                               float* __restrict__ dinv, int n) {
    __shared__ int cnt[NPB];
    __shared__ int scn[NPB];
    int b = blockIdx.x;
    int t = threadIdx.x;
    cnt[t] = 0;
    __syncthreads();
    int m = min(binCnt[b], CAPE);
    const int* eb = binned + b * CAPE;
    for (int i = t; i < m; i += 1024)
        atomicAdd(&cnt[eb[i] & MASK], 1);
    __syncthreads();
    int v = cnt[t];
    scn[t] = v;
    __syncthreads();
    // Hillis-Steele inclusive scan over 1024
    for (int off = 1; off < NPB; off <<= 1) {
        int a = (t >= off) ? scn[t - off] : 0;
        __syncthreads();
        scn[t] += a;
        __syncthreads();
    }
    int excl = scn[t] - v;
    int node = b * NPB + t;
    if (node < n) {
        gptr[node] = b * CAPE + excl;
        gcnt[node] = v;
        dinv[node] = rsqrtf((float)(v + 1));
    }
    cnt[t] = excl;  // reuse as cursor
    __syncthreads();
    for (int i = t; i < m; i += 1024) {
        int e = eb[i];
        int slot = atomicAdd(&cnt[e & MASK], 1);
        csr[b * CAPE + slot] = e >> SHIFT;
    }
}

// --- z1[i] = dinv[i] * (x[i] @ W1), LDS-staged x (validated) -----------------
__global__ void __launch_bounds__(256) k_xform1(const float* __restrict__ x,
                                                const float* __restrict__ W1,
                                                const float* __restrict__ dinv,
                                                float* __restrict__ z1, int n) {
    __shared__ float sW[25 * 16];
    __shared__ float tile[4][64 * 25];
    int w = threadIdx.x >> 6, lane = threadIdx.x & 63;
    for (int t = threadIdx.x; t < 25 * 16; t += 256) sW[t] = W1[t];
    long blockRow = (long)blockIdx.x * 256;
    long waveRow = blockRow + w * 64;
    const float* src = x + waveRow * 25;
    long rem = (long)n * 25 - waveRow * 25;
#pragma unroll
    for (int k = 0; k < 25; k++) {
        int idx = k * 64 + lane;
        tile[w][idx] = (idx < rem) ? src[idx] : 0.f;
    }
    __syncthreads();
    long node = blockRow + threadIdx.x;
    if (node >= n) return;
    float xi[25];
#pragma unroll
    for (int k = 0; k < 25; k++) xi[k] = tile[w][lane * 25 + k];
    float di = dinv[node];
    float s[16];
#pragma unroll
    for (int c = 0; c < 16; c++) {
        float a = 0.f;
#pragma unroll
        for (int k = 0; k < 25; k++) a = fmaf(xi[k], sW[k * 16 + c], a);
        s[c] = a * di;
    }
    float4* o = (float4*)(z1 + node * 16);
#pragma unroll
    for (int q = 0; q < 4; q++) o[q] = make_float4(s[q * 4], s[q * 4 + 1], s[q * 4 + 2], s[q * 4 + 3]);
}

// --- gather layer 1 + bias/relu + @W2 (16 lanes per node, 4-unrolled) --------
__global__ void k_gather1(const int* __restrict__ ptr, const int* __restrict__ cnt,
                          const int* __restrict__ csr, const float* __restrict__ z1,
                          const float* __restrict__ dinv,
                          const float* __restrict__ b1, const float* __restrict__ W2,
                          float* __restrict__ z2, int n) {
    int g = threadIdx.x >> 4;
    int c = threadIdx.x & 15;
    int node = blockIdx.x * 16 + g;
    if (node >= n) return;
    int beg = ptr[node], d = cnt[node];
    float acc = z1[(size_t)node * 16 + c];  // self loop (z1 pre-scaled by dinv)
    int e = 0;
    for (; e + 4 <= d; e += 4) {
        int s0 = csr[beg + e], s1 = csr[beg + e + 1];
        int s2 = csr[beg + e + 2], s3 = csr[beg + e + 3];
        float v0 = z1[(size_t)s0 * 16 + c];
        float v1 = z1[(size_t)s1 * 16 + c];
        float v2 = z1[(size_t)s2 * 16 + c];
        float v3 = z1[(size_t)s3 * 16 + c];
        acc += ((v0 + v1) + (v2 + v3));
    }
    for (; e < d; e++) acc += z1[(size_t)csr[beg + e] * 16 + c];
    float di = dinv[node];
    float h = fmaxf(fmaf(di, acc, b1[c]), 0.f);
    float p0 = h * W2[c * 2 + 0];
    float p1 = h * W2[c * 2 + 1];
#pragma unroll
    for (int m = 1; m < 16; m <<= 1) {
        p0 += __shfl_xor(p0, m, 16);
        p1 += __shfl_xor(p1, m, 16);
    }
    if (c == 0) {
        z2[(size_t)node * 2 + 0] = di * p0;
        z2[(size_t)node * 2 + 1] = di * p1;
    }
}

// --- gather layer 2 + bias + log_softmax(2) ----------------------------------
__global__ void k_gather2(const int* __restrict__ ptr, const int* __restrict__ cnt,
                          const int* __restrict__ csr, const float* __restrict__ z2,
                          const float* __restrict__ dinv,
                          const float* __restrict__ b2, float* __restrict__ out, int n) {
    int node = blockIdx.x * blockDim.x + threadIdx.x;
    if (node >= n) return;
    int beg = ptr[node], d = cnt[node];
    float2 self = ((const float2*)z2)[node];
    float a0 = self.x, a1 = self.y;
    int e = 0;
    for (; e + 4 <= d; e += 4) {
        float2 v0 = ((const float2*)z2)[csr[beg + e]];
        float2 v1 = ((const float2*)z2)[csr[beg + e + 1]];
        float2 v2 = ((const float2*)z2)[csr[beg + e + 2]];
        float2 v3 = ((const float2*)z2)[csr[beg + e + 3]];
        a0 += ((v0.x + v1.x) + (v2.x + v3.x));
        a1 += ((v0.y + v1.y) + (v2.y + v3.y));
    }
    for (; e < d; e++) {
        float2 v = ((const float2*)z2)[csr[beg + e]];
        a0 += v.x; a1 += v.y;
    }
    float di = dinv[node];
    float h0 = fmaf(di, a0, b2[0]);
    float h1 = fmaf(di, a1, b2[1]);
    float m = fmaxf(h0, h1);
    float lse = m + log1pf(expf(fminf(h0, h1) - m));
    out[(size_t)node * 2 + 0] = h0 - lse;
    out[(size_t)node * 2 + 1] = h1 - lse;
}

// ===================== fallback: round-2 CSR pipeline (347us proven) =========

__global__ void k_zero(int* cnt, int n) {
    int i = blockIdx.x * blockDim.x + threadIdx.x;
    if (i < n) cnt[i] = 0;
}

__global__ void k_count_pos(const int* __restrict__ col, int e,
                            int* __restrict__ cnt, int* __restrict__ pos) {
    int i = blockIdx.x * blockDim.x + threadIdx.x;
    if (i < e) pos[i] = atomicAdd(&cnt[col[i]], 1);
}

__global__ void k_scan1(const int* __restrict__ cnt, int n,
                        int* __restrict__ excl, int* __restrict__ bsum) {
    __shared__ int s[256];
    int i = blockIdx.x * 256 + threadIdx.x;
    int v = (i < n) ? cnt[i] : 0;
    s[threadIdx.x] = v;
    __syncthreads();
    for (int off = 1; off < 256; off <<= 1) {
        int t = (threadIdx.x >= off) ? s[threadIdx.x - off] : 0;
        __syncthreads();
        s[threadIdx.x] += t;
        __syncthreads();
    }
    if (i < n) excl[i] = s[threadIdx.x] - v;
    if (threadIdx.x == 255) bsum[blockIdx.x] = s[255];
}

__global__ void k_scan2(int* __restrict__ bsum, int nb) {
    __shared__ int s[1024];
    int v = (threadIdx.x < nb) ? bsum[threadIdx.x] : 0;
    s[threadIdx.x] = v;
    __syncthreads();
    for (int off = 1; off < 1024; off <<= 1) {
        int t = (threadIdx.x >= off) ? s[threadIdx.x - off] : 0;
        __syncthreads();
        s[threadIdx.x] += t;
        __syncthreads();
    }
    if (threadIdx.x < nb) bsum[threadIdx.x] = s[threadIdx.x] - v;
}

__global__ void k_scan3(int* __restrict__ excl, const int* __restrict__ boff, int n) {
    int i = blockIdx.x * 256 + threadIdx.x;
    if (i < n) excl[i] += boff[blockIdx.x];
}

__global__ void k_place(const int* __restrict__ row, const int* __restrict__ col,
                        const int* __restrict__ pos, const int* __restrict__ ptr,
                        int e, int* __restrict__ csr) {
    int i = blockIdx.x * blockDim.x + threadIdx.x;
    if (i >= e) return;
    csr[ptr[col[i]] + pos[i]] = row[i];
}

__global__ void k_dinv_from_cnt(const int* __restrict__ cnt, float* __restrict__ dinv, int n) {
    int i = blockIdx.x * blockDim.x + threadIdx.x;
    if (i < n) dinv[i] = rsqrtf((float)(cnt[i] + 1));
}

// ============================== host launcher ================================

extern "C" void kernel_launch(void* const* d_in, const int* in_sizes, int n_in,
                              void* d_out, int out_size, void* d_ws, size_t ws_size,
                              hipStream_t stream) {
    const float* x  = (const float*)d_in[0];
    const int*   ei = (const int*)d_in[1];
    const float* W1 = (const float*)d_in[2];
    const float* b1 = (const float*)d_in[3];
    const float* W2 = (const float*)d_in[4];
    const float* b2 = (const float*)d_in[5];
    float* out = (float*)d_out;

    const int N = in_sizes[0] / 25;
    const int E = in_sizes[1] / 2;
    const int* row = ei;
    const int* col = ei + E;

    const int nbins = (N + NPB - 1) / NPB;
    const int gN = (N + THREADS - 1) / THREADS;
    const int gE = (E + THREADS - 1) / THREADS;

    size_t off = 0;
    auto take = [&](size_t bytes) { size_t o = off; off = (off + bytes + 255) & ~(size_t)255; return o; };
    size_t o_binCnt = take(MAX_BINS * sizeof(int));
    size_t o_binned = take((size_t)nbins * CAPE * sizeof(int));
    size_t o_csr    = take((size_t)nbins * CAPE * sizeof(int));
    size_t o_ptr    = take((size_t)N * sizeof(int));
    size_t o_cnt    = take((size_t)N * sizeof(int));
    size_t o_dinv   = take((size_t)N * sizeof(float));
    size_t o_z1     = take((size_t)N * 16 * sizeof(float));
    size_t o_z2     = take((size_t)N * 2 * sizeof(float));
    size_t need_v5 = off;

    // capacity guard (FIXED from round 5: was CAPE*3/4 which rejected the
    // design case). Multinomial bin load: mu = E/nbins, sigma = sqrt(mu).
    // Require mu + 8*sigma < CAPE.
    double mu = (double)E / (double)nbins;
    bool cap_ok = (mu + 8.0 * sqrt(mu)) < (double)CAPE;
    const int per = (E + BIN_BLOCKS - 1) / BIN_BLOCKS;
    bool lds_ok = (size_t)per * sizeof(int) <= 160 * 1024 - 4096;  // k_bin dynamic LDS
    bool use_v5 = (nbins <= MAX_BINS) && (ws_size >= need_v5) &&
                  (N < (1 << 21)) && cap_ok && lds_ok;

    if (use_v5) {
        char* wsb = (char*)d_ws;
        int*   binCnt = (int*)(wsb + o_binCnt);
        int*   binned = (int*)(wsb + o_binned);
        int*   csr    = (int*)(wsb + o_csr);
        int*   ptr    = (int*)(wsb + o_ptr);
        int*   cnt    = (int*)(wsb + o_cnt);
        float* dinv   = (float*)(wsb + o_dinv);
        float* z1     = (float*)(wsb + o_z1);
        float* z2     = (float*)(wsb + o_z2);

        hipMemsetAsync(binCnt, 0, MAX_BINS * sizeof(int), stream);
        k_bin<<<BIN_BLOCKS, 256, per * sizeof(int), stream>>>(row, col, E, binCnt, binned);
        k_sort<<<nbins, 1024, 0, stream>>>(binned, binCnt, csr, ptr, cnt, dinv, N);
        k_xform1<<<gN, 256, 0, stream>>>(x, W1, dinv, z1, N);
        k_gather1<<<(N + 15) / 16, 256, 0, stream>>>(ptr, cnt, csr, z1, dinv, b1, W2, z2, N);
        k_gather2<<<gN, THREADS, 0, stream>>>(ptr, cnt, csr, z2, dinv, b2, out, N);
    } else {
        char* w = (char*)d_ws;
        int*   cnt  = (int*)w;    w += (size_t)N * sizeof(int);
        int*   ptr  = (int*)w;    w += (size_t)N * sizeof(int);
        int*   pos  = (int*)w;    w += (size_t)E * sizeof(int);
        int*   csr  = (int*)w;    w += (size_t)E * sizeof(int);
        int*   bsum = (int*)w;    w += (size_t)1024 * sizeof(int);
        float* dinv = (float*)w;  w += (size_t)N * sizeof(float);
        float* z1   = (float*)w;  w += (size_t)N * 16 * sizeof(float);
        float* z2   = (float*)w;  w += (size_t)N * 2 * sizeof(float);
        const int NB = (N + 255) / 256;

        k_zero<<<gN, THREADS, 0, stream>>>(cnt, N);
        k_count_pos<<<gE, THREADS, 0, stream>>>(col, E, cnt, pos);
        k_scan1<<<NB, 256, 0, stream>>>(cnt, N, ptr, bsum);
        k_scan2<<<1, 1024, 0, stream>>>(bsum, NB);
        k_scan3<<<NB, 256, 0, stream>>>(ptr, bsum, N);
        k_place<<<gE, THREADS, 0, stream>>>(row, col, pos, ptr, E, csr);
        k_dinv_from_cnt<<<gN, THREADS, 0, stream>>>(cnt, dinv, N);
        k_xform1<<<gN, 256, 0, stream>>>(x, W1, dinv, z1, N);
        k_gather1<<<(N + 15) / 16, 256, 0, stream>>>(ptr, cnt, csr, z1, dinv, b1, W2, z2, N);
        k_gather2<<<gN, THREADS, 0, stream>>>(ptr, cnt, csr, z2, dinv, b2, out, N);
    }
}

// Round 7
// 250.293 us; speedup vs baseline: 2.2188x; 1.0002x over previous
//
#include <hip/hip_runtime.h>
#include <hip/hip_fp16.h>
#include <math.h>

#define THREADS 256
#define NPB 512           // nodes per bin
#define SHIFT 9
#define MASK 511
#define MAX_BINS 256
#define CAPE 18432        // per-bin edge capacity (mu=16.3k at E=3.2M/196 bins, +16 sigma)
#define BIN_BLOCKS 1024

// ===================== stage 1: bin edges by target>>9 =======================
// Per-block LDS counting sort into up to 256 bins, coalesced global flush.

__global__ void __launch_bounds__(256) k_bin(const int* __restrict__ row,
                                             const int* __restrict__ col,
                                             int e, int* __restrict__ binCnt,
                                             int* __restrict__ binned) {
    __shared__ int hist[MAX_BINS];
    __shared__ int lofs[MAX_BINS];
    __shared__ int baseg[MAX_BINS];
    __shared__ int cur[MAX_BINS];
    __shared__ int lscan[MAX_BINS];
    extern __shared__ int sortbuf[];
    int per = (e + gridDim.x - 1) / gridDim.x;
    int e0 = blockIdx.x * per;
    int e1 = min(e0 + per, e);
    if (e1 <= e0) return;
    int tid = threadIdx.x;
    for (int t = tid; t < MAX_BINS; t += 256) { hist[t] = 0; cur[t] = 0; }
    __syncthreads();
    for (int i = e0 + tid; i < e1; i += 256)
        atomicAdd(&hist[col[i] >> SHIFT], 1);
    __syncthreads();
    if (tid < MAX_BINS) {
        int h = hist[tid];
        baseg[tid] = (h > 0) ? atomicAdd(&binCnt[tid], h) : 0;
        lscan[tid] = h;
    }
    __syncthreads();
    // block-parallel inclusive scan over MAX_BINS (==256==blockDim)
    for (int off = 1; off < MAX_BINS; off <<= 1) {
        int a = (tid >= off && tid < MAX_BINS) ? lscan[tid - off] : 0;
        __syncthreads();
        if (tid < MAX_BINS) lscan[tid] += a;
        __syncthreads();
    }
    if (tid < MAX_BINS) lofs[tid] = lscan[tid] - hist[tid];
    __syncthreads();
    for (int i = e0 + tid; i < e1; i += 256) {
        int c = col[i];
        int b = c >> SHIFT;
        int slot = lofs[b] + atomicAdd(&cur[b], 1);
        sortbuf[slot] = (row[i] << SHIFT) | (c & MASK);  // row < 2^17 -> fits 26 bits
    }
    __syncthreads();
    for (int b = 0; b < MAX_BINS; b++) {
        int h = hist[b];
        if (h == 0) continue;
        int gb = b * CAPE + baseg[b];
        int lb = lofs[b];
        int lim = (b + 1) * CAPE;
        for (int i = tid; i < h; i += 256) {
            int dst = gb + i;
            if (dst < lim) binned[dst] = sortbuf[lb + i];  // overflow guard (P~0)
        }
    }
}

// ======= stage 2: per-bin counting sort -> CSR + deg + ptr + dinv ============
// Scattered csr stores confined to a 72KB window per block -> L2 writeback
// absorbs them, no global atomics.

__global__ void __launch_bounds__(512) k_sort(const int* __restrict__ binned,
                                              const int* __restrict__ binCnt,
                                              int* __restrict__ csr,
                                              int* __restrict__ gptr,
                                              int* __restrict__ gcnt,
                                              float* __restrict__ dinv, int n) {
    __shared__ int cnt[NPB];
    __shared__ int scn[NPB];
    int b = blockIdx.x;
    int t = threadIdx.x;
    cnt[t] = 0;
    __syncthreads();
    int m = min(binCnt[b], CAPE);
    const int* eb = binned + b * CAPE;
    for (int i = t; i < m; i += 512)
        atomicAdd(&cnt[eb[i] & MASK], 1);
    __syncthreads();
    int v = cnt[t];
    scn[t] = v;
    __syncthreads();
    for (int off = 1; off < NPB; off <<= 1) {
        int a = (t >= off) ? scn[t - off] : 0;
        __syncthreads();
        scn[t] += a;
        __syncthreads();
    }
    int excl = scn[t] - v;
    int node = b * NPB + t;
    if (node < n) {
        gptr[node] = b * CAPE + excl;
        gcnt[node] = v;
        dinv[node] = rsqrtf((float)(v + 1));
    }
    cnt[t] = excl;  // reuse as cursor
    __syncthreads();
    for (int i = t; i < m; i += 512) {
        int e = eb[i];
        int slot = atomicAdd(&cnt[e & MASK], 1);
        csr[b * CAPE + slot] = e >> SHIFT;
    }
}

// --- z1h[i] = fp16( dinv[i] * (x[i] @ W1) ), LDS-staged x --------------------
__global__ void __launch_bounds__(256) k_xform1(const float* __restrict__ x,
                                                const float* __restrict__ W1,
                                                const float* __restrict__ dinv,
                                                __half* __restrict__ z1h, int n) {
    __shared__ float sW[25 * 16];
    __shared__ float tile[4][64 * 25];
    int w = threadIdx.x >> 6, lane = threadIdx.x & 63;
    for (int t = threadIdx.x; t < 25 * 16; t += 256) sW[t] = W1[t];
    long blockRow = (long)blockIdx.x * 256;
    long waveRow = blockRow + w * 64;
    const float* src = x + waveRow * 25;
    long rem = (long)n * 25 - waveRow * 25;
#pragma unroll
    for (int k = 0; k < 25; k++) {
        int idx = k * 64 + lane;
        tile[w][idx] = (idx < rem) ? src[idx] : 0.f;
    }
    __syncthreads();
    long node = blockRow + threadIdx.x;
    if (node >= n) return;
    float xi[25];
#pragma unroll
    for (int k = 0; k < 25; k++) xi[k] = tile[w][lane * 25 + k];
    float di = dinv[node];
    union { int4 v[2]; __half h[16]; } u;
#pragma unroll
    for (int c = 0; c < 16; c++) {
        float a = 0.f;
#pragma unroll
        for (int k = 0; k < 25; k++) a = fmaf(xi[k], sW[k * 16 + c], a);
        u.h[c] = __float2half(a * di);
    }
    int4* o = (int4*)(z1h + node * 16);
    o[0] = u.v[0];
    o[1] = u.v[1];
}

// --- gather layer 1 + bias/relu + @W2 (16 lanes per node, 4-unrolled) --------
__global__ void k_gather1(const int* __restrict__ ptr, const int* __restrict__ cnt,
                          const int* __restrict__ csr, const __half* __restrict__ z1h,
                          const float* __restrict__ dinv,
                          const float* __restrict__ b1, const float* __restrict__ W2,
                          float* __restrict__ z2, int n) {
    int g = threadIdx.x >> 4;
    int c = threadIdx.x & 15;
    int node = blockIdx.x * 16 + g;
    if (node >= n) return;
    int beg = ptr[node], d = cnt[node];
    float acc = __half2float(z1h[(size_t)node * 16 + c]);  // self loop
    int e = 0;
    for (; e + 4 <= d; e += 4) {
        int s0 = csr[beg + e], s1 = csr[beg + e + 1];
        int s2 = csr[beg + e + 2], s3 = csr[beg + e + 3];
        float v0 = __half2float(z1h[(size_t)s0 * 16 + c]);
        float v1 = __half2float(z1h[(size_t)s1 * 16 + c]);
        float v2 = __half2float(z1h[(size_t)s2 * 16 + c]);
        float v3 = __half2float(z1h[(size_t)s3 * 16 + c]);
        acc += ((v0 + v1) + (v2 + v3));
    }
    for (; e < d; e++) acc += __half2float(z1h[(size_t)csr[beg + e] * 16 + c]);
    float di = dinv[node];
    float h = fmaxf(fmaf(di, acc, b1[c]), 0.f);
    float p0 = h * W2[c * 2 + 0];
    float p1 = h * W2[c * 2 + 1];
#pragma unroll
    for (int m = 1; m < 16; m <<= 1) {
        p0 += __shfl_xor(p0, m, 16);
        p1 += __shfl_xor(p1, m, 16);
    }
    if (c == 0) {
        z2[(size_t)node * 2 + 0] = di * p0;
        z2[(size_t)node * 2 + 1] = di * p1;
    }
}

// --- gather layer 2 + bias + log_softmax(2) ----------------------------------
__global__ void k_gather2(const int* __restrict__ ptr, const int* __restrict__ cnt,
                          const int* __restrict__ csr, const float* __restrict__ z2,
                          const float* __restrict__ dinv,
                          const float* __restrict__ b2, float* __restrict__ out, int n) {
    int node = blockIdx.x * blockDim.x + threadIdx.x;
    if (node >= n) return;
    int beg = ptr[node], d = cnt[node];
    float2 self = ((const float2*)z2)[node];
    float a0 = self.x, a1 = self.y;
    int e = 0;
    for (; e + 4 <= d; e += 4) {
        float2 v0 = ((const float2*)z2)[csr[beg + e]];
        float2 v1 = ((const float2*)z2)[csr[beg + e + 1]];
        float2 v2 = ((const float2*)z2)[csr[beg + e + 2]];
        float2 v3 = ((const float2*)z2)[csr[beg + e + 3]];
        a0 += ((v0.x + v1.x) + (v2.x + v3.x));
        a1 += ((v0.y + v1.y) + (v2.y + v3.y));
    }
    for (; e < d; e++) {
        float2 v = ((const float2*)z2)[csr[beg + e]];
        a0 += v.x; a1 += v.y;
    }
    float di = dinv[node];
    float h0 = fmaf(di, a0, b2[0]);
    float h1 = fmaf(di, a1, b2[1]);
    float m = fmaxf(h0, h1);
    float lse = m + log1pf(expf(fminf(h0, h1) - m));
    out[(size_t)node * 2 + 0] = h0 - lse;
    out[(size_t)node * 2 + 1] = h1 - lse;
}

// ===================== fallback: round-2 CSR pipeline ========================

__global__ void k_zero(int* cnt, int n) {
    int i = blockIdx.x * blockDim.x + threadIdx.x;
    if (i < n) cnt[i] = 0;
}

__global__ void k_count_pos(const int* __restrict__ col, int e,
                            int* __restrict__ cnt, int* __restrict__ pos) {
    int i = blockIdx.x * blockDim.x + threadIdx.x;
    if (i < e) pos[i] = atomicAdd(&cnt[col[i]], 1);
}

__global__ void k_scan1(const int* __restrict__ cnt, int n,
                        int* __restrict__ excl, int* __restrict__ bsum) {
    __shared__ int s[256];
    int i = blockIdx.x * 256 + threadIdx.x;
    int v = (i < n) ? cnt[i] : 0;
    s[threadIdx.x] = v;
    __syncthreads();
    for (int off = 1; off < 256; off <<= 1) {
        int t = (threadIdx.x >= off) ? s[threadIdx.x - off] : 0;
        __syncthreads();
        s[threadIdx.x] += t;
        __syncthreads();
    }
    if (i < n) excl[i] = s[threadIdx.x] - v;
    if (threadIdx.x == 255) bsum[blockIdx.x] = s[255];
}

__global__ void k_scan2(int* __restrict__ bsum, int nb) {
    __shared__ int s[1024];
    int v = (threadIdx.x < nb) ? bsum[threadIdx.x] : 0;
    s[threadIdx.x] = v;
    __syncthreads();
    for (int off = 1; off < 1024; off <<= 1) {
        int t = (threadIdx.x >= off) ? s[threadIdx.x - off] : 0;
        __syncthreads();
        s[threadIdx.x] += t;
        __syncthreads();
    }
    if (threadIdx.x < nb) bsum[threadIdx.x] = s[threadIdx.x] - v;
}

__global__ void k_scan3(int* __restrict__ excl, const int* __restrict__ boff, int n) {
    int i = blockIdx.x * 256 + threadIdx.x;
    if (i < n) excl[i] += boff[blockIdx.x];
}

__global__ void k_place(const int* __restrict__ row, const int* __restrict__ col,
                        const int* __restrict__ pos, const int* __restrict__ ptr,
                        int e, int* __restrict__ csr) {
    int i = blockIdx.x * blockDim.x + threadIdx.x;
    if (i >= e) return;
    csr[ptr[col[i]] + pos[i]] = row[i];
}

__global__ void k_dinv_from_cnt(const int* __restrict__ cnt, float* __restrict__ dinv, int n) {
    int i = blockIdx.x * blockDim.x + threadIdx.x;
    if (i < n) dinv[i] = rsqrtf((float)(cnt[i] + 1));
}

// ============================== host launcher ================================

extern "C" void kernel_launch(void* const* d_in, const int* in_sizes, int n_in,
                              void* d_out, int out_size, void* d_ws, size_t ws_size,
                              hipStream_t stream) {
    const float* x  = (const float*)d_in[0];
    const int*   ei = (const int*)d_in[1];
    const float* W1 = (const float*)d_in[2];
    const float* b1 = (const float*)d_in[3];
    const float* W2 = (const float*)d_in[4];
    const float* b2 = (const float*)d_in[5];
    float* out = (float*)d_out;

    const int N = in_sizes[0] / 25;
    const int E = in_sizes[1] / 2;
    const int* row = ei;
    const int* col = ei + E;

    const int nbins = (N + NPB - 1) / NPB;
    const int gN = (N + THREADS - 1) / THREADS;
    const int gE = (E + THREADS - 1) / THREADS;

    size_t off = 0;
    auto take = [&](size_t bytes) { size_t o = off; off = (off + bytes + 255) & ~(size_t)255; return o; };
    size_t o_binCnt = take(MAX_BINS * sizeof(int));
    size_t o_binned = take((size_t)nbins * CAPE * sizeof(int));
    size_t o_csr    = take((size_t)nbins * CAPE * sizeof(int));
    size_t o_ptr    = take((size_t)N * sizeof(int));
    size_t o_cnt    = take((size_t)N * sizeof(int));
    size_t o_dinv   = take((size_t)N * sizeof(float));
    size_t o_z1h    = take((size_t)N * 16 * sizeof(__half));
    size_t o_z2     = take((size_t)N * 2 * sizeof(float));
    size_t need_v6 = off;

    // capacity guard: multinomial bin load mu = E/nbins, sigma = sqrt(mu).
    double mu = (double)E / (double)nbins;
    bool cap_ok = (mu + 8.0 * sqrt(mu)) < (double)CAPE;
    const int per = (E + BIN_BLOCKS - 1) / BIN_BLOCKS;
    bool lds_ok = (size_t)per * sizeof(int) <= 140 * 1024;  // k_bin dynamic LDS
    bool use_v6 = (nbins <= MAX_BINS) && (ws_size >= need_v6) &&
                  (N < (1 << 17)) && cap_ok && lds_ok;

    char* wsb = (char*)d_ws;
    if (use_v6) {
        int*    binCnt = (int*)(wsb + o_binCnt);
        int*    binned = (int*)(wsb + o_binned);
        int*    csr    = (int*)(wsb + o_csr);
        int*    ptr    = (int*)(wsb + o_ptr);
        int*    cnt    = (int*)(wsb + o_cnt);
        float*  dinv   = (float*)(wsb + o_dinv);
        __half* z1h    = (__half*)(wsb + o_z1h);
        float*  z2     = (float*)(wsb + o_z2);

        hipMemsetAsync(binCnt, 0, MAX_BINS * sizeof(int), stream);
        k_bin<<<BIN_BLOCKS, 256, per * sizeof(int), stream>>>(row, col, E, binCnt, binned);
        k_sort<<<nbins, 512, 0, stream>>>(binned, binCnt, csr, ptr, cnt, dinv, N);
        k_xform1<<<gN, 256, 0, stream>>>(x, W1, dinv, z1h, N);
        k_gather1<<<(N + 15) / 16, 256, 0, stream>>>(ptr, cnt, csr, z1h, dinv, b1, W2, z2, N);
        k_gather2<<<gN, THREADS, 0, stream>>>(ptr, cnt, csr, z2, dinv, b2, out, N);
    } else {
        char* w = wsb;
        int*    cnt  = (int*)w;    w += (size_t)N * sizeof(int);
        int*    ptr  = (int*)w;    w += (size_t)N * sizeof(int);
        int*    pos  = (int*)w;    w += (size_t)E * sizeof(int);
        int*    csr  = (int*)w;    w += (size_t)E * sizeof(int);
        int*    bsum = (int*)w;    w += (size_t)1024 * sizeof(int);
        float*  dinv = (float*)w;  w += (size_t)N * sizeof(float);
        __half* z1h  = (__half*)w; w += (size_t)N * 16 * sizeof(__half);
        float*  z2   = (float*)w;  w += (size_t)N * 2 * sizeof(float);
        const int NB = (N + 255) / 256;

        k_zero<<<gN, THREADS, 0, stream>>>(cnt, N);
        k_count_pos<<<gE, THREADS, 0, stream>>>(col, E, cnt, pos);
        k_scan1<<<NB, 256, 0, stream>>>(cnt, N, ptr, bsum);
        k_scan2<<<1, 1024, 0, stream>>>(bsum, NB);
        k_scan3<<<NB, 256, 0, stream>>>(ptr, bsum, N);
        k_place<<<gE, THREADS, 0, stream>>>(row, col, pos, ptr, E, csr);
        k_dinv_from_cnt<<<gN, THREADS, 0, stream>>>(cnt, dinv, N);
        k_xform1<<<gN, 256, 0, stream>>>(x, W1, dinv, z1h, N);
        k_gather1<<<(N + 15) / 16, 256, 0, stream>>>(ptr, cnt, csr, z1h, dinv, b1, W2, z2, N);
        k_gather2<<<gN, THREADS, 0, stream>>>(ptr, cnt, csr, z2, dinv, b2, out, N);
    }
}

// Round 8
// 232.539 us; speedup vs baseline: 2.3882x; 1.0763x over previous
//
#include <hip/hip_runtime.h>
#include <hip/hip_fp16.h>
#include <math.h>

#define THREADS 256
#define NPB 1024          // nodes per bin
#define SHIFT 10
#define MASK 1023
#define MAX_BINS 128
#define CAPE 36864        // per-bin edge capacity (mu=32.6k at E=3.2M/98 bins, +23 sigma)
#define BIN_BLOCKS 2048

// ===================== stage 1: bin edges by target>>10 ======================
// Single-pass: load row+col once, stash packed edge + bin id in LDS, LDS hist,
// reserve global space (128 atomics/block), direct global scatter into the
// block's contiguous per-bin windows (L2 merges into full lines).

__global__ void __launch_bounds__(256) k_bin(const int* __restrict__ row,
                                             const int* __restrict__ col,
                                             int e, int* __restrict__ binCnt,
                                             int* __restrict__ binned) {
    __shared__ int hist[MAX_BINS];
    __shared__ int cur[MAX_BINS];
    __shared__ int baseg[MAX_BINS];
    extern __shared__ int dyn[];
    int per = (e + gridDim.x - 1) / gridDim.x;
    int e0 = blockIdx.x * per;
    int e1 = min(e0 + per, e);
    if (e1 <= e0) return;
    int cntL = e1 - e0;
    int* sbuf = dyn;                              // per packed edges
    unsigned char* sbin = (unsigned char*)(dyn + per);  // per bin ids
    int tid = threadIdx.x;
    for (int t = tid; t < MAX_BINS; t += 256) { hist[t] = 0; cur[t] = 0; }
    __syncthreads();
    for (int li = tid; li < cntL; li += 256) {
        int c = col[e0 + li];
        int r = row[e0 + li];
        int b = c >> SHIFT;
        sbuf[li] = (r << SHIFT) | (c & MASK);
        sbin[li] = (unsigned char)b;
        atomicAdd(&hist[b], 1);
    }
    __syncthreads();
    if (tid < MAX_BINS) {
        int h = hist[tid];
        baseg[tid] = (h > 0) ? atomicAdd(&binCnt[tid], h) : 0;
    }
    __syncthreads();
    for (int li = tid; li < cntL; li += 256) {
        int b = sbin[li];
        int pos = baseg[b] + atomicAdd(&cur[b], 1);
        if (pos < CAPE) binned[b * CAPE + pos] = sbuf[li];  // overflow guard (P~0)
    }
}

// ======= stage 2: per-bin counting sort -> CSR + deg + ptr + dinv ============
// (round-6 proven config: 1024 threads, 1024-node bins, 144KB scatter window)

__global__ void __launch_bounds__(1024) k_sort(const int* __restrict__ binned,
                                               const int* __restrict__ binCnt,
                                               int* __restrict__ csr,
                                               int* __restrict__ gptr,
                                               int* __restrict__ gcnt,
                                               float* __restrict__ dinv, int n) {
    __shared__ int cnt[NPB];
    __shared__ int scn[NPB];
    int b = blockIdx.x;
    int t = threadIdx.x;
    cnt[t] = 0;
    __syncthreads();
    int m = min(binCnt[b], CAPE);
    const int* eb = binned + b * CAPE;
    for (int i = t; i < m; i += 1024)
        atomicAdd(&cnt[eb[i] & MASK], 1);
    __syncthreads();
    int v = cnt[t];
    scn[t] = v;
    __syncthreads();
    for (int off = 1; off < NPB; off <<= 1) {
        int a = (t >= off) ? scn[t - off] : 0;
        __syncthreads();
        scn[t] += a;
        __syncthreads();
    }
    int excl = scn[t] - v;
    int node = b * NPB + t;
    if (node < n) {
        gptr[node] = b * CAPE + excl;
        gcnt[node] = v;
        dinv[node] = rsqrtf((float)(v + 1));
    }
    cnt[t] = excl;  // reuse as cursor
    __syncthreads();
    for (int i = t; i < m; i += 1024) {
        int e = eb[i];
        int slot = atomicAdd(&cnt[e & MASK], 1);
        csr[b * CAPE + slot] = e >> SHIFT;
    }
}

// --- z1h[i] = fp16( dinv[i] * (x[i] @ W1) ), LDS-staged x --------------------
__global__ void __launch_bounds__(256) k_xform1(const float* __restrict__ x,
                                                const float* __restrict__ W1,
                                                const float* __restrict__ dinv,
                                                __half* __restrict__ z1h, int n) {
    __shared__ float sW[25 * 16];
    __shared__ float tile[4][64 * 25];
    int w = threadIdx.x >> 6, lane = threadIdx.x & 63;
    for (int t = threadIdx.x; t < 25 * 16; t += 256) sW[t] = W1[t];
    long blockRow = (long)blockIdx.x * 256;
    long waveRow = blockRow + w * 64;
    const float* src = x + waveRow * 25;
    long rem = (long)n * 25 - waveRow * 25;
#pragma unroll
    for (int k = 0; k < 25; k++) {
        int idx = k * 64 + lane;
        tile[w][idx] = (idx < rem) ? src[idx] : 0.f;
    }
    __syncthreads();
    long node = blockRow + threadIdx.x;
    if (node >= n) return;
    float xi[25];
#pragma unroll
    for (int k = 0; k < 25; k++) xi[k] = tile[w][lane * 25 + k];
    float di = dinv[node];
    union { int4 v[2]; __half h[16]; } u;
#pragma unroll
    for (int c = 0; c < 16; c++) {
        float a = 0.f;
#pragma unroll
        for (int k = 0; k < 25; k++) a = fmaf(xi[k], sW[k * 16 + c], a);
        u.h[c] = __float2half(a * di);
    }
    int4* o = (int4*)(z1h + node * 16);
    o[0] = u.v[0];
    o[1] = u.v[1];
}

// --- gather layer 1 + bias/relu + @W2 (16 lanes per node, 4-unrolled) --------
__global__ void k_gather1(const int* __restrict__ ptr, const int* __restrict__ cnt,
                          const int* __restrict__ csr, const __half* __restrict__ z1h,
                          const float* __restrict__ dinv,
                          const float* __restrict__ b1, const float* __restrict__ W2,
                          float* __restrict__ z2, int n) {
    int g = threadIdx.x >> 4;
    int c = threadIdx.x & 15;
    int node = blockIdx.x * 16 + g;
    if (node >= n) return;
    int beg = ptr[node], d = cnt[node];
    float acc = __half2float(z1h[(size_t)node * 16 + c]);  // self loop
    int e = 0;
    for (; e + 4 <= d; e += 4) {
        int s0 = csr[beg + e], s1 = csr[beg + e + 1];
        int s2 = csr[beg + e + 2], s3 = csr[beg + e + 3];
        float v0 = __half2float(z1h[(size_t)s0 * 16 + c]);
        float v1 = __half2float(z1h[(size_t)s1 * 16 + c]);
        float v2 = __half2float(z1h[(size_t)s2 * 16 + c]);
        float v3 = __half2float(z1h[(size_t)s3 * 16 + c]);
        acc += ((v0 + v1) + (v2 + v3));
    }
    for (; e < d; e++) acc += __half2float(z1h[(size_t)csr[beg + e] * 16 + c]);
    float di = dinv[node];
    float h = fmaxf(fmaf(di, acc, b1[c]), 0.f);
    float p0 = h * W2[c * 2 + 0];
    float p1 = h * W2[c * 2 + 1];
#pragma unroll
    for (int m = 1; m < 16; m <<= 1) {
        p0 += __shfl_xor(p0, m, 16);
        p1 += __shfl_xor(p1, m, 16);
    }
    if (c == 0) {
        z2[(size_t)node * 2 + 0] = di * p0;
        z2[(size_t)node * 2 + 1] = di * p1;
    }
}

// --- gather layer 2 + bias + log_softmax(2) ----------------------------------
__global__ void k_gather2(const int* __restrict__ ptr, const int* __restrict__ cnt,
                          const int* __restrict__ csr, const float* __restrict__ z2,
                          const float* __restrict__ dinv,
                          const float* __restrict__ b2, float* __restrict__ out, int n) {
    int node = blockIdx.x * blockDim.x + threadIdx.x;
    if (node >= n) return;
    int beg = ptr[node], d = cnt[node];
    float2 self = ((const float2*)z2)[node];
    float a0 = self.x, a1 = self.y;
    int e = 0;
    for (; e + 4 <= d; e += 4) {
        float2 v0 = ((const float2*)z2)[csr[beg + e]];
        float2 v1 = ((const float2*)z2)[csr[beg + e + 1]];
        float2 v2 = ((const float2*)z2)[csr[beg + e + 2]];
        float2 v3 = ((const float2*)z2)[csr[beg + e + 3]];
        a0 += ((v0.x + v1.x) + (v2.x + v3.x));
        a1 += ((v0.y + v1.y) + (v2.y + v3.y));
    }
    for (; e < d; e++) {
        float2 v = ((const float2*)z2)[csr[beg + e]];
        a0 += v.x; a1 += v.y;
    }
    float di = dinv[node];
    float h0 = fmaf(di, a0, b2[0]);
    float h1 = fmaf(di, a1, b2[1]);
    float m = fmaxf(h0, h1);
    float lse = m + log1pf(expf(fminf(h0, h1) - m));
    out[(size_t)node * 2 + 0] = h0 - lse;
    out[(size_t)node * 2 + 1] = h1 - lse;
}

// ===================== fallback: round-2 CSR pipeline ========================

__global__ void k_zero(int* cnt, int n) {
    int i = blockIdx.x * blockDim.x + threadIdx.x;
    if (i < n) cnt[i] = 0;
}

__global__ void k_count_pos(const int* __restrict__ col, int e,
                            int* __restrict__ cnt, int* __restrict__ pos) {
    int i = blockIdx.x * blockDim.x + threadIdx.x;
    if (i < e) pos[i] = atomicAdd(&cnt[col[i]], 1);
}

__global__ void k_scan1(const int* __restrict__ cnt, int n,
                        int* __restrict__ excl, int* __restrict__ bsum) {
    __shared__ int s[256];
    int i = blockIdx.x * 256 + threadIdx.x;
    int v = (i < n) ? cnt[i] : 0;
    s[threadIdx.x] = v;
    __syncthreads();
    for (int off = 1; off < 256; off <<= 1) {
        int t = (threadIdx.x >= off) ? s[threadIdx.x - off] : 0;
        __syncthreads();
        s[threadIdx.x] += t;
        __syncthreads();
    }
    if (i < n) excl[i] = s[threadIdx.x] - v;
    if (threadIdx.x == 255) bsum[blockIdx.x] = s[255];
}

__global__ void k_scan2(int* __restrict__ bsum, int nb) {
    __shared__ int s[1024];
    int v = (threadIdx.x < nb) ? bsum[threadIdx.x] : 0;
    s[threadIdx.x] = v;
    __syncthreads();
    for (int off = 1; off < 1024; off <<= 1) {
        int t = (threadIdx.x >= off) ? s[threadIdx.x - off] : 0;
        __syncthreads();
        s[threadIdx.x] += t;
        __syncthreads();
    }
    if (threadIdx.x < nb) bsum[threadIdx.x] = s[threadIdx.x] - v;
}

__global__ void k_scan3(int* __restrict__ excl, const int* __restrict__ boff, int n) {
    int i = blockIdx.x * 256 + threadIdx.x;
    if (i < n) excl[i] += boff[blockIdx.x];
}

__global__ void k_place(const int* __restrict__ row, const int* __restrict__ col,
                        const int* __restrict__ pos, const int* __restrict__ ptr,
                        int e, int* __restrict__ csr) {
    int i = blockIdx.x * blockDim.x + threadIdx.x;
    if (i >= e) return;
    csr[ptr[col[i]] + pos[i]] = row[i];
}

__global__ void k_dinv_from_cnt(const int* __restrict__ cnt, float* __restrict__ dinv, int n) {
    int i = blockIdx.x * blockDim.x + threadIdx.x;
    if (i < n) dinv[i] = rsqrtf((float)(cnt[i] + 1));
}

// ============================== host launcher ================================

extern "C" void kernel_launch(void* const* d_in, const int* in_sizes, int n_in,
                              void* d_out, int out_size, void* d_ws, size_t ws_size,
                              hipStream_t stream) {
    const float* x  = (const float*)d_in[0];
    const int*   ei = (const int*)d_in[1];
    const float* W1 = (const float*)d_in[2];
    const float* b1 = (const float*)d_in[3];
    const float* W2 = (const float*)d_in[4];
    const float* b2 = (const float*)d_in[5];
    float* out = (float*)d_out;

    const int N = in_sizes[0] / 25;
    const int E = in_sizes[1] / 2;
    const int* row = ei;
    const int* col = ei + E;

    const int nbins = (N + NPB - 1) / NPB;
    const int gN = (N + THREADS - 1) / THREADS;
    const int gE = (E + THREADS - 1) / THREADS;

    size_t off = 0;
    auto take = [&](size_t bytes) { size_t o = off; off = (off + bytes + 255) & ~(size_t)255; return o; };
    size_t o_binCnt = take(MAX_BINS * sizeof(int));
    size_t o_binned = take((size_t)nbins * CAPE * sizeof(int));
    size_t o_csr    = take((size_t)nbins * CAPE * sizeof(int));
    size_t o_ptr    = take((size_t)N * sizeof(int));
    size_t o_cnt    = take((size_t)N * sizeof(int));
    size_t o_dinv   = take((size_t)N * sizeof(float));
    size_t o_z1h    = take((size_t)N * 16 * sizeof(__half));
    size_t o_z2     = take((size_t)N * 2 * sizeof(float));
    size_t need_v7 = off;

    // guards: multinomial bin load mu = E/nbins, sigma = sqrt(mu);
    // k_bin dynamic LDS = per*(4+1) bytes must leave occupancy headroom.
    double mu = (double)E / (double)nbins;
    bool cap_ok = (mu + 8.0 * sqrt(mu)) < (double)CAPE;
    const int per = (E + BIN_BLOCKS - 1) / BIN_BLOCKS;
    size_t dynLds = (size_t)per * 5 + 64;
    bool lds_ok = dynLds <= 64 * 1024;
    bool use_v7 = (nbins <= MAX_BINS) && (ws_size >= need_v7) &&
                  (N <= NPB * MAX_BINS) && (N < (1 << 17)) && cap_ok && lds_ok;

    char* wsb = (char*)d_ws;
    if (use_v7) {
        int*    binCnt = (int*)(wsb + o_binCnt);
        int*    binned = (int*)(wsb + o_binned);
        int*    csr    = (int*)(wsb + o_csr);
        int*    ptr    = (int*)(wsb + o_ptr);
        int*    cnt    = (int*)(wsb + o_cnt);
        float*  dinv   = (float*)(wsb + o_dinv);
        __half* z1h    = (__half*)(wsb + o_z1h);
        float*  z2     = (float*)(wsb + o_z2);

        hipMemsetAsync(binCnt, 0, MAX_BINS * sizeof(int), stream);
        k_bin<<<BIN_BLOCKS, 256, dynLds, stream>>>(row, col, E, binCnt, binned);
        k_sort<<<nbins, 1024, 0, stream>>>(binned, binCnt, csr, ptr, cnt, dinv, N);
        k_xform1<<<gN, 256, 0, stream>>>(x, W1, dinv, z1h, N);
        k_gather1<<<(N + 15) / 16, 256, 0, stream>>>(ptr, cnt, csr, z1h, dinv, b1, W2, z2, N);
        k_gather2<<<gN, THREADS, 0, stream>>>(ptr, cnt, csr, z2, dinv, b2, out, N);
    } else {
        char* w = wsb;
        int*    cnt  = (int*)w;    w += (size_t)N * sizeof(int);
        int*    ptr  = (int*)w;    w += (size_t)N * sizeof(int);
        int*    pos  = (int*)w;    w += (size_t)E * sizeof(int);
        int*    csr  = (int*)w;    w += (size_t)E * sizeof(int);
        int*    bsum = (int*)w;    w += (size_t)1024 * sizeof(int);
        float*  dinv = (float*)w;  w += (size_t)N * sizeof(float);
        __half* z1h  = (__half*)w; w += (size_t)N * 16 * sizeof(__half);
        float*  z2   = (float*)w;  w += (size_t)N * 2 * sizeof(float);
        const int NB = (N + 255) / 256;

        k_zero<<<gN, THREADS, 0, stream>>>(cnt, N);
        k_count_pos<<<gE, THREADS, 0, stream>>>(col, E, cnt, pos);
        k_scan1<<<NB, 256, 0, stream>>>(cnt, N, ptr, bsum);
        k_scan2<<<1, 1024, 0, stream>>>(bsum, NB);
        k_scan3<<<NB, 256, 0, stream>>>(ptr, bsum, N);
        k_place<<<gE, THREADS, 0, stream>>>(row, col, pos, ptr, E, csr);
        k_dinv_from_cnt<<<gN, THREADS, 0, stream>>>(cnt, dinv, N);
        k_xform1<<<gN, 256, 0, stream>>>(x, W1, dinv, z1h, N);
        k_gather1<<<(N + 15) / 16, 256, 0, stream>>>(ptr, cnt, csr, z1h, dinv, b1, W2, z2, N);
        k_gather2<<<gN, THREADS, 0, stream>>>(ptr, cnt, csr, z2, dinv, b2, out, N);
    }
}

// Round 9
// 225.200 us; speedup vs baseline: 2.4660x; 1.0326x over previous
//
#include <hip/hip_runtime.h>
#include <hip/hip_fp16.h>
#include <math.h>

#define THREADS 256
#define NPB 1024          // nodes per bin
#define SHIFT 10
#define MASK 1023
#define MAX_BINS 128
#define CAPE 36864        // per-bin edge capacity (mu=32.6k at E=3.2M/98 bins, +23 sigma)
#define BIN_BLOCKS 2048

// ===================== stage 1: bin edges by target>>10 ======================
// Single-pass: load row+col once, stash packed edge + bin id in LDS, LDS hist,
// reserve global space (128 atomics/block), direct global scatter into the
// block's contiguous per-bin windows (L2 merges into full lines).

__global__ void __launch_bounds__(256) k_bin(const int* __restrict__ row,
                                             const int* __restrict__ col,
                                             int e, int* __restrict__ binCnt,
                                             int* __restrict__ binned) {
    __shared__ int hist[MAX_BINS];
    __shared__ int cur[MAX_BINS];
    __shared__ int baseg[MAX_BINS];
    extern __shared__ int dyn[];
    int per = (e + gridDim.x - 1) / gridDim.x;
    int e0 = blockIdx.x * per;
    int e1 = min(e0 + per, e);
    if (e1 <= e0) return;
    int cntL = e1 - e0;
    int* sbuf = dyn;                                    // packed edges
    unsigned char* sbin = (unsigned char*)(dyn + per);  // bin ids
    int tid = threadIdx.x;
    for (int t = tid; t < MAX_BINS; t += 256) { hist[t] = 0; cur[t] = 0; }
    __syncthreads();
    for (int li = tid; li < cntL; li += 256) {
        int c = col[e0 + li];
        int r = row[e0 + li];
        int b = c >> SHIFT;
        sbuf[li] = (r << SHIFT) | (c & MASK);
        sbin[li] = (unsigned char)b;
        atomicAdd(&hist[b], 1);
    }
    __syncthreads();
    if (tid < MAX_BINS) {
        int h = hist[tid];
        baseg[tid] = (h > 0) ? atomicAdd(&binCnt[tid], h) : 0;
    }
    __syncthreads();
    for (int li = tid; li < cntL; li += 256) {
        int b = sbin[li];
        int pos = baseg[b] + atomicAdd(&cur[b], 1);
        if (pos < CAPE) binned[b * CAPE + pos] = sbuf[li];  // overflow guard (P~0)
    }
}

// ======= stage 2: per-bin counting sort -> CSR + deg + ptr + dinv ============

__global__ void __launch_bounds__(1024) k_sort(const int* __restrict__ binned,
                                               const int* __restrict__ binCnt,
                                               int* __restrict__ csr,
                                               int* __restrict__ gptr,
                                               int* __restrict__ gcnt,
                                               float* __restrict__ dinv, int n) {
    __shared__ int cnt[NPB];
    __shared__ int scn[NPB];
    int b = blockIdx.x;
    int t = threadIdx.x;
    cnt[t] = 0;
    __syncthreads();
    int m = min(binCnt[b], CAPE);
    const int* eb = binned + b * CAPE;
    for (int i = t; i < m; i += 1024)
        atomicAdd(&cnt[eb[i] & MASK], 1);
    __syncthreads();
    int v = cnt[t];
    scn[t] = v;
    __syncthreads();
    for (int off = 1; off < NPB; off <<= 1) {
        int a = (t >= off) ? scn[t - off] : 0;
        __syncthreads();
        scn[t] += a;
        __syncthreads();
    }
    int excl = scn[t] - v;
    int node = b * NPB + t;
    if (node < n) {
        gptr[node] = b * CAPE + excl;
        gcnt[node] = v;
        dinv[node] = rsqrtf((float)(v + 1));
    }
    cnt[t] = excl;  // reuse as cursor
    __syncthreads();
    for (int i = t; i < m; i += 1024) {
        int e = eb[i];
        int slot = atomicAdd(&cnt[e & MASK], 1);
        csr[b * CAPE + slot] = e >> SHIFT;
    }
}

// --- z1h[i] = fp16( dinv[i] * (x[i] @ W1) ), LDS-staged x --------------------
__global__ void __launch_bounds__(256) k_xform1(const float* __restrict__ x,
                                                const float* __restrict__ W1,
                                                const float* __restrict__ dinv,
                                                __half* __restrict__ z1h, int n) {
    __shared__ float sW[25 * 16];
    __shared__ float tile[4][64 * 25];
    int w = threadIdx.x >> 6, lane = threadIdx.x & 63;
    for (int t = threadIdx.x; t < 25 * 16; t += 256) sW[t] = W1[t];
    long blockRow = (long)blockIdx.x * 256;
    long waveRow = blockRow + w * 64;
    const float* src = x + waveRow * 25;
    long rem = (long)n * 25 - waveRow * 25;
#pragma unroll
    for (int k = 0; k < 25; k++) {
        int idx = k * 64 + lane;
        tile[w][idx] = (idx < rem) ? src[idx] : 0.f;
    }
    __syncthreads();
    long node = blockRow + threadIdx.x;
    if (node >= n) return;
    float xi[25];
#pragma unroll
    for (int k = 0; k < 25; k++) xi[k] = tile[w][lane * 25 + k];
    float di = dinv[node];
    union { int4 v[2]; __half h[16]; } u;
#pragma unroll
    for (int c = 0; c < 16; c++) {
        float a = 0.f;
#pragma unroll
        for (int k = 0; k < 25; k++) a = fmaf(xi[k], sW[k * 16 + c], a);
        u.h[c] = __float2half(a * di);
    }
    int4* o = (int4*)(z1h + node * 16);
    o[0] = u.v[0];
    o[1] = u.v[1];
}

// --- gather layer 1 + bias/relu + @W2: 8 lanes/node, half2 loads -------------
__global__ void k_gather1(const int* __restrict__ ptr, const int* __restrict__ cnt,
                          const int* __restrict__ csr, const __half* __restrict__ z1h,
                          const float* __restrict__ dinv,
                          const float* __restrict__ b1, const float* __restrict__ W2,
                          __half2* __restrict__ z2h, int n) {
    int g = threadIdx.x >> 3;   // 32 node-groups per 256-block
    int c2 = threadIdx.x & 7;   // feature-pair lane (features 2c2, 2c2+1)
    int node = blockIdx.x * 32 + g;
    if (node >= n) return;
    const __half2* z1p = (const __half2*)z1h;  // node*8 + c2
    int beg = ptr[node], d = cnt[node];
    __half2 sv = z1p[(size_t)node * 8 + c2];   // self loop (z1 pre-scaled)
    float a0 = __low2float(sv), a1 = __high2float(sv);
    int e = 0;
    for (; e + 4 <= d; e += 4) {
        int s0 = csr[beg + e], s1 = csr[beg + e + 1];
        int s2 = csr[beg + e + 2], s3 = csr[beg + e + 3];
        __half2 v0 = z1p[(size_t)s0 * 8 + c2];
        __half2 v1 = z1p[(size_t)s1 * 8 + c2];
        __half2 v2 = z1p[(size_t)s2 * 8 + c2];
        __half2 v3 = z1p[(size_t)s3 * 8 + c2];
        a0 += (__low2float(v0) + __low2float(v1)) + (__low2float(v2) + __low2float(v3));
        a1 += (__high2float(v0) + __high2float(v1)) + (__high2float(v2) + __high2float(v3));
    }
    for (; e < d; e++) {
        __half2 v = z1p[(size_t)csr[beg + e] * 8 + c2];
        a0 += __low2float(v);
        a1 += __high2float(v);
    }
    float di = dinv[node];
    int cA = c2 * 2, cB = c2 * 2 + 1;
    float hA = fmaxf(fmaf(di, a0, b1[cA]), 0.f);
    float hB = fmaxf(fmaf(di, a1, b1[cB]), 0.f);
    float p0 = hA * W2[cA * 2 + 0] + hB * W2[cB * 2 + 0];
    float p1 = hA * W2[cA * 2 + 1] + hB * W2[cB * 2 + 1];
#pragma unroll
    for (int m = 1; m < 8; m <<= 1) {
        p0 += __shfl_xor(p0, m, 8);
        p1 += __shfl_xor(p1, m, 8);
    }
    if (c2 == 0) z2h[node] = __floats2half2_rn(di * p0, di * p1);
}

// --- gather layer 2 + bias + log_softmax(2), half2 reads ---------------------
__global__ void k_gather2(const int* __restrict__ ptr, const int* __restrict__ cnt,
                          const int* __restrict__ csr, const __half2* __restrict__ z2h,
                          const float* __restrict__ dinv,
                          const float* __restrict__ b2, float* __restrict__ out, int n) {
    int node = blockIdx.x * blockDim.x + threadIdx.x;
    if (node >= n) return;
    int beg = ptr[node], d = cnt[node];
    __half2 self = z2h[node];
    float a0 = __low2float(self), a1 = __high2float(self);
    int e = 0;
    for (; e + 4 <= d; e += 4) {
        __half2 v0 = z2h[csr[beg + e]];
        __half2 v1 = z2h[csr[beg + e + 1]];
        __half2 v2 = z2h[csr[beg + e + 2]];
        __half2 v3 = z2h[csr[beg + e + 3]];
        a0 += (__low2float(v0) + __low2float(v1)) + (__low2float(v2) + __low2float(v3));
        a1 += (__high2float(v0) + __high2float(v1)) + (__high2float(v2) + __high2float(v3));
    }
    for (; e < d; e++) {
        __half2 v = z2h[csr[beg + e]];
        a0 += __low2float(v);
        a1 += __high2float(v);
    }
    float di = dinv[node];
    float h0 = fmaf(di, a0, b2[0]);
    float h1 = fmaf(di, a1, b2[1]);
    float m = fmaxf(h0, h1);
    float lse = m + log1pf(expf(fminf(h0, h1) - m));
    out[(size_t)node * 2 + 0] = h0 - lse;
    out[(size_t)node * 2 + 1] = h1 - lse;
}

// ===================== fallback: round-2 CSR pipeline ========================

__global__ void k_zero(int* cnt, int n) {
    int i = blockIdx.x * blockDim.x + threadIdx.x;
    if (i < n) cnt[i] = 0;
}

__global__ void k_count_pos(const int* __restrict__ col, int e,
                            int* __restrict__ cnt, int* __restrict__ pos) {
    int i = blockIdx.x * blockDim.x + threadIdx.x;
    if (i < e) pos[i] = atomicAdd(&cnt[col[i]], 1);
}

__global__ void k_scan1(const int* __restrict__ cnt, int n,
                        int* __restrict__ excl, int* __restrict__ bsum) {
    __shared__ int s[256];
    int i = blockIdx.x * 256 + threadIdx.x;
    int v = (i < n) ? cnt[i] : 0;
    s[threadIdx.x] = v;
    __syncthreads();
    for (int off = 1; off < 256; off <<= 1) {
        int t = (threadIdx.x >= off) ? s[threadIdx.x - off] : 0;
        __syncthreads();
        s[threadIdx.x] += t;
        __syncthreads();
    }
    if (i < n) excl[i] = s[threadIdx.x] - v;
    if (threadIdx.x == 255) bsum[blockIdx.x] = s[255];
}

__global__ void k_scan2(int* __restrict__ bsum, int nb) {
    __shared__ int s[1024];
    int v = (threadIdx.x < nb) ? bsum[threadIdx.x] : 0;
    s[threadIdx.x] = v;
    __syncthreads();
    for (int off = 1; off < 1024; off <<= 1) {
        int t = (threadIdx.x >= off) ? s[threadIdx.x - off] : 0;
        __syncthreads();
        s[threadIdx.x] += t;
        __syncthreads();
    }
    if (threadIdx.x < nb) bsum[threadIdx.x] = s[threadIdx.x] - v;
}

__global__ void k_scan3(int* __restrict__ excl, const int* __restrict__ boff, int n) {
    int i = blockIdx.x * 256 + threadIdx.x;
    if (i < n) excl[i] += boff[blockIdx.x];
}

__global__ void k_place(const int* __restrict__ row, const int* __restrict__ col,
                        const int* __restrict__ pos, const int* __restrict__ ptr,
                        int e, int* __restrict__ csr) {
    int i = blockIdx.x * blockDim.x + threadIdx.x;
    if (i >= e) return;
    csr[ptr[col[i]] + pos[i]] = row[i];
}

__global__ void k_dinv_from_cnt(const int* __restrict__ cnt, float* __restrict__ dinv, int n) {
    int i = blockIdx.x * blockDim.x + threadIdx.x;
    if (i < n) dinv[i] = rsqrtf((float)(cnt[i] + 1));
}

// ============================== host launcher ================================

extern "C" void kernel_launch(void* const* d_in, const int* in_sizes, int n_in,
                              void* d_out, int out_size, void* d_ws, size_t ws_size,
                              hipStream_t stream) {
    const float* x  = (const float*)d_in[0];
    const int*   ei = (const int*)d_in[1];
    const float* W1 = (const float*)d_in[2];
    const float* b1 = (const float*)d_in[3];
    const float* W2 = (const float*)d_in[4];
    const float* b2 = (const float*)d_in[5];
    float* out = (float*)d_out;

    const int N = in_sizes[0] / 25;
    const int E = in_sizes[1] / 2;
    const int* row = ei;
    const int* col = ei + E;

    const int nbins = (N + NPB - 1) / NPB;
    const int gN = (N + THREADS - 1) / THREADS;
    const int gE = (E + THREADS - 1) / THREADS;

    size_t off = 0;
    auto take = [&](size_t bytes) { size_t o = off; off = (off + bytes + 255) & ~(size_t)255; return o; };
    size_t o_binCnt = take(MAX_BINS * sizeof(int));
    size_t o_binned = take((size_t)nbins * CAPE * sizeof(int));
    size_t o_csr    = take((size_t)nbins * CAPE * sizeof(int));
    size_t o_ptr    = take((size_t)N * sizeof(int));
    size_t o_cnt    = take((size_t)N * sizeof(int));
    size_t o_dinv   = take((size_t)N * sizeof(float));
    size_t o_z1h    = take((size_t)N * 16 * sizeof(__half));
    size_t o_z2h    = take((size_t)N * sizeof(__half2));
    size_t need_v8 = off;

    double mu = (double)E / (double)nbins;
    bool cap_ok = (mu + 8.0 * sqrt(mu)) < (double)CAPE;
    const int per = (E + BIN_BLOCKS - 1) / BIN_BLOCKS;
    size_t dynLds = (size_t)per * 5 + 64;
    bool lds_ok = dynLds <= 64 * 1024;
    bool use_v8 = (nbins <= MAX_BINS) && (ws_size >= need_v8) &&
                  (N <= NPB * MAX_BINS) && (N < (1 << 17)) && cap_ok && lds_ok;

    char* wsb = (char*)d_ws;
    if (use_v8) {
        int*     binCnt = (int*)(wsb + o_binCnt);
        int*     binned = (int*)(wsb + o_binned);
        int*     csr    = (int*)(wsb + o_csr);
        int*     ptr    = (int*)(wsb + o_ptr);
        int*     cnt    = (int*)(wsb + o_cnt);
        float*   dinv   = (float*)(wsb + o_dinv);
        __half*  z1h    = (__half*)(wsb + o_z1h);
        __half2* z2h    = (__half2*)(wsb + o_z2h);

        hipMemsetAsync(binCnt, 0, MAX_BINS * sizeof(int), stream);
        k_bin<<<BIN_BLOCKS, 256, dynLds, stream>>>(row, col, E, binCnt, binned);
        k_sort<<<nbins, 1024, 0, stream>>>(binned, binCnt, csr, ptr, cnt, dinv, N);
        k_xform1<<<gN, 256, 0, stream>>>(x, W1, dinv, z1h, N);
        k_gather1<<<(N + 31) / 32, 256, 0, stream>>>(ptr, cnt, csr, z1h, dinv, b1, W2, z2h, N);
        k_gather2<<<gN, THREADS, 0, stream>>>(ptr, cnt, csr, z2h, dinv, b2, out, N);
    } else {
        char* w = wsb;
        int*     cnt  = (int*)w;     w += (size_t)N * sizeof(int);
        int*     ptr  = (int*)w;     w += (size_t)N * sizeof(int);
        int*     pos  = (int*)w;     w += (size_t)E * sizeof(int);
        int*     csr  = (int*)w;     w += (size_t)E * sizeof(int);
        int*     bsum = (int*)w;     w += (size_t)1024 * sizeof(int);
        float*   dinv = (float*)w;   w += (size_t)N * sizeof(float);
        __half*  z1h  = (__half*)w;  w += (size_t)N * 16 * sizeof(__half);
        __half2* z2h  = (__half2*)w; w += (size_t)N * sizeof(__half2);
        const int NB = (N + 255) / 256;

        k_zero<<<gN, THREADS, 0, stream>>>(cnt, N);
        k_count_pos<<<gE, THREADS, 0, stream>>>(col, E, cnt, pos);
        k_scan1<<<NB, 256, 0, stream>>>(cnt, N, ptr, bsum);
        k_scan2<<<1, 1024, 0, stream>>>(bsum, NB);
        k_scan3<<<NB, 256, 0, stream>>>(ptr, bsum, N);
        k_place<<<gE, THREADS, 0, stream>>>(row, col, pos, ptr, E, csr);
        k_dinv_from_cnt<<<gN, THREADS, 0, stream>>>(cnt, dinv, N);
        k_xform1<<<gN, 256, 0, stream>>>(x, W1, dinv, z1h, N);
        k_gather1<<<(N + 31) / 32, 256, 0, stream>>>(ptr, cnt, csr, z1h, dinv, b1, W2, z2h, N);
        k_gather2<<<gN, THREADS, 0, stream>>>(ptr, cnt, csr, z2h, dinv, b2, out, N);
    }
}

// Round 10
// 203.095 us; speedup vs baseline: 2.7344x; 1.1088x over previous
//
#include <hip/hip_runtime.h>
#include <hip/hip_fp16.h>
#include <math.h>

#define THREADS 256
#define NPB 1024          // nodes per bin
#define SHIFT 10
#define MASK 1023
#define MAX_BINS 128
#define CAPE 36864        // per-bin edge capacity (mu=32.6k at E=3.2M/98 bins, +23 sigma)
#define BIN_BLOCKS 512

// ===================== stage 1: bin edges by target>>10 ======================
// Single pass: int4 stash of packed edge + bin id in LDS, LDS histogram,
// global reservation (128 atomics/block), in-LDS counting sort, then
// WAVE-PARALLEL COALESCED flush: wave w flushes bins w,w+4,... each bin's
// ~49-entry run hits consecutive global addresses (full-line stores), fixing
// the ~50-lines-per-store scatter that made R8's k_bin transaction-bound.

__global__ void __launch_bounds__(256) k_bin(const int* __restrict__ row,
                                             const int* __restrict__ col,
                                             int e, int* __restrict__ binCnt,
                                             int* __restrict__ binned) {
    __shared__ int hist[MAX_BINS];
    __shared__ int cur[MAX_BINS];
    __shared__ int baseg[MAX_BINS];
    __shared__ int lofs[MAX_BINS];
    __shared__ int scn[MAX_BINS];
    extern __shared__ int dyn[];
    int per = (((e + (int)gridDim.x - 1) / (int)gridDim.x) + 3) & ~3;
    int e0 = blockIdx.x * per;
    if (e0 >= e) return;
    int e1 = min(e0 + per, e);
    int cntL = e1 - e0;
    int* sbuf  = dyn;                                   // packed, edge order
    int* sbuf2 = dyn + per;                             // packed, bin-sorted
    unsigned char* sbin = (unsigned char*)(dyn + 2 * per);  // bin ids
    int tid = threadIdx.x;
    for (int t = tid; t < MAX_BINS; t += 256) { hist[t] = 0; cur[t] = 0; }
    __syncthreads();
    // pass A: vectorized load, stash, histogram
    int nq = cntL >> 2;
    const int4* r4 = (const int4*)(row + e0);
    const int4* c4 = (const int4*)(col + e0);
    for (int q = tid; q < nq; q += 256) {
        int4 r = r4[q], c = c4[q];
        int b0 = c.x >> SHIFT, b1 = c.y >> SHIFT, b2 = c.z >> SHIFT, b3 = c.w >> SHIFT;
        ((int4*)sbuf)[q] = make_int4((r.x << SHIFT) | (c.x & MASK),
                                     (r.y << SHIFT) | (c.y & MASK),
                                     (r.z << SHIFT) | (c.z & MASK),
                                     (r.w << SHIFT) | (c.w & MASK));
        *((uchar4*)(sbin + q * 4)) = make_uchar4((unsigned char)b0, (unsigned char)b1,
                                                 (unsigned char)b2, (unsigned char)b3);
        atomicAdd(&hist[b0], 1); atomicAdd(&hist[b1], 1);
        atomicAdd(&hist[b2], 1); atomicAdd(&hist[b3], 1);
    }
    for (int li = (nq << 2) + tid; li < cntL; li += 256) {  // scalar tail
        int c = col[e0 + li], r = row[e0 + li], b = c >> SHIFT;
        sbuf[li] = (r << SHIFT) | (c & MASK);
        sbin[li] = (unsigned char)b;
        atomicAdd(&hist[b], 1);
    }
    __syncthreads();
    // reserve global space + local exclusive scan over bins
    if (tid < MAX_BINS) {
        int h = hist[tid];
        baseg[tid] = (h > 0) ? atomicAdd(&binCnt[tid], h) : 0;
        scn[tid] = h;
    }
    __syncthreads();
    for (int off = 1; off < MAX_BINS; off <<= 1) {
        int a = (tid >= off && tid < MAX_BINS) ? scn[tid - off] : 0;
        __syncthreads();
        if (tid < MAX_BINS) scn[tid] += a;
        __syncthreads();
    }
    if (tid < MAX_BINS) lofs[tid] = scn[tid] - hist[tid];
    __syncthreads();
    // pass B: in-LDS counting-sort scatter
    for (int li = tid; li < cntL; li += 256) {
        int b = sbin[li];
        int p = lofs[b] + atomicAdd(&cur[b], 1);
        sbuf2[p] = sbuf[li];
    }
    __syncthreads();
    // pass C: wave-parallel coalesced flush (consecutive lanes -> consecutive addrs)
    int wv = tid >> 6, ln = tid & 63;
    for (int b = wv; b < MAX_BINS; b += 4) {
        int len = hist[b];
        int lo = lofs[b];
        int gb = baseg[b];
        for (int i = ln; i < len; i += 64) {
            int pos = gb + i;
            if (pos < CAPE) binned[b * CAPE + pos] = sbuf2[lo + i];  // overflow guard (P~0)
        }
    }
}

// ======= stage 2: per-bin counting sort -> CSR + deg + ptr + dinv ============

__global__ void __launch_bounds__(1024) k_sort(const int* __restrict__ binned,
                                               const int* __restrict__ binCnt,
                                               int* __restrict__ csr,
                                               int* __restrict__ gptr,
                                               int* __restrict__ gcnt,
                                               float* __restrict__ dinv, int n) {
    __shared__ int cnt[NPB];
    __shared__ int scn[NPB];
    int b = blockIdx.x;
    int t = threadIdx.x;
    cnt[t] = 0;
    __syncthreads();
    int m = min(binCnt[b], CAPE);
    const int* eb = binned + b * CAPE;
    for (int i = t; i < m; i += 1024)
        atomicAdd(&cnt[eb[i] & MASK], 1);
    __syncthreads();
    int v = cnt[t];
    scn[t] = v;
    __syncthreads();
    for (int off = 1; off < NPB; off <<= 1) {
        int a = (t >= off) ? scn[t - off] : 0;
        __syncthreads();
        scn[t] += a;
        __syncthreads();
    }
    int excl = scn[t] - v;
    int node = b * NPB + t;
    if (node < n) {
        gptr[node] = b * CAPE + excl;
        gcnt[node] = v;
        dinv[node] = rsqrtf((float)(v + 1));
    }
    cnt[t] = excl;  // reuse as cursor
    __syncthreads();
    for (int i = t; i < m; i += 1024) {
        int e = eb[i];
        int slot = atomicAdd(&cnt[e & MASK], 1);
        csr[b * CAPE + slot] = e >> SHIFT;
    }
}

// --- z1h[i] = fp16( dinv[i] * (x[i] @ W1) ), LDS-staged x --------------------
__global__ void __launch_bounds__(256) k_xform1(const float* __restrict__ x,
                                                const float* __restrict__ W1,
                                                const float* __restrict__ dinv,
                                                __half* __restrict__ z1h, int n) {
    __shared__ float sW[25 * 16];
    __shared__ float tile[4][64 * 25];
    int w = threadIdx.x >> 6, lane = threadIdx.x & 63;
    for (int t = threadIdx.x; t < 25 * 16; t += 256) sW[t] = W1[t];
    long blockRow = (long)blockIdx.x * 256;
    long waveRow = blockRow + w * 64;
    const float* src = x + waveRow * 25;
    long rem = (long)n * 25 - waveRow * 25;
#pragma unroll
    for (int k = 0; k < 25; k++) {
        int idx = k * 64 + lane;
        tile[w][idx] = (idx < rem) ? src[idx] : 0.f;
    }
    __syncthreads();
    long node = blockRow + threadIdx.x;
    if (node >= n) return;
    float xi[25];
#pragma unroll
    for (int k = 0; k < 25; k++) xi[k] = tile[w][lane * 25 + k];
    float di = dinv[node];
    union { int4 v[2]; __half h[16]; } u;
#pragma unroll
    for (int c = 0; c < 16; c++) {
        float a = 0.f;
#pragma unroll
        for (int k = 0; k < 25; k++) a = fmaf(xi[k], sW[k * 16 + c], a);
        u.h[c] = __float2half(a * di);
    }
    int4* o = (int4*)(z1h + node * 16);
    o[0] = u.v[0];
    o[1] = u.v[1];
}

// --- gather layer 1 + bias/relu + @W2: 8 lanes/node, half2 loads -------------
__global__ void k_gather1(const int* __restrict__ ptr, const int* __restrict__ cnt,
                          const int* __restrict__ csr, const __half* __restrict__ z1h,
                          const float* __restrict__ dinv,
                          const float* __restrict__ b1, const float* __restrict__ W2,
                          __half2* __restrict__ z2h, int n) {
    int g = threadIdx.x >> 3;
    int c2 = threadIdx.x & 7;
    int node = blockIdx.x * 32 + g;
    if (node >= n) return;
    const __half2* z1p = (const __half2*)z1h;
    int beg = ptr[node], d = cnt[node];
    __half2 sv = z1p[(size_t)node * 8 + c2];
    float a0 = __low2float(sv), a1 = __high2float(sv);
    int e = 0;
    for (; e + 4 <= d; e += 4) {
        int s0 = csr[beg + e], s1 = csr[beg + e + 1];
        int s2 = csr[beg + e + 2], s3 = csr[beg + e + 3];
        __half2 v0 = z1p[(size_t)s0 * 8 + c2];
        __half2 v1 = z1p[(size_t)s1 * 8 + c2];
        __half2 v2 = z1p[(size_t)s2 * 8 + c2];
        __half2 v3 = z1p[(size_t)s3 * 8 + c2];
        a0 += (__low2float(v0) + __low2float(v1)) + (__low2float(v2) + __low2float(v3));
        a1 += (__high2float(v0) + __high2float(v1)) + (__high2float(v2) + __high2float(v3));
    }
    for (; e < d; e++) {
        __half2 v = z1p[(size_t)csr[beg + e] * 8 + c2];
        a0 += __low2float(v);
        a1 += __high2float(v);
    }
    float di = dinv[node];
    int cA = c2 * 2, cB = c2 * 2 + 1;
    float hA = fmaxf(fmaf(di, a0, b1[cA]), 0.f);
    float hB = fmaxf(fmaf(di, a1, b1[cB]), 0.f);
    float p0 = hA * W2[cA * 2 + 0] + hB * W2[cB * 2 + 0];
    float p1 = hA * W2[cA * 2 + 1] + hB * W2[cB * 2 + 1];
#pragma unroll
    for (int m = 1; m < 8; m <<= 1) {
        p0 += __shfl_xor(p0, m, 8);
        p1 += __shfl_xor(p1, m, 8);
    }
    if (c2 == 0) z2h[node] = __floats2half2_rn(di * p0, di * p1);
}

// --- gather layer 2 + bias + log_softmax(2), half2 reads ---------------------
__global__ void k_gather2(const int* __restrict__ ptr, const int* __restrict__ cnt,
                          const int* __restrict__ csr, const __half2* __restrict__ z2h,
                          const float* __restrict__ dinv,
                          const float* __restrict__ b2, float* __restrict__ out, int n) {
    int node = blockIdx.x * blockDim.x + threadIdx.x;
    if (node >= n) return;
    int beg = ptr[node], d = cnt[node];
    __half2 self = z2h[node];
    float a0 = __low2float(self), a1 = __high2float(self);
    int e = 0;
    for (; e + 4 <= d; e += 4) {
        __half2 v0 = z2h[csr[beg + e]];
        __half2 v1 = z2h[csr[beg + e + 1]];
        __half2 v2 = z2h[csr[beg + e + 2]];
        __half2 v3 = z2h[csr[beg + e + 3]];
        a0 += (__low2float(v0) + __low2float(v1)) + (__low2float(v2) + __low2float(v3));
        a1 += (__high2float(v0) + __high2float(v1)) + (__high2float(v2) + __high2float(v3));
    }
    for (; e < d; e++) {
        __half2 v = z2h[csr[beg + e]];
        a0 += __low2float(v);
        a1 += __high2float(v);
    }
    float di = dinv[node];
    float h0 = fmaf(di, a0, b2[0]);
    float h1 = fmaf(di, a1, b2[1]);
    float m = fmaxf(h0, h1);
    float lse = m + log1pf(expf(fminf(h0, h1) - m));
    out[(size_t)node * 2 + 0] = h0 - lse;
    out[(size_t)node * 2 + 1] = h1 - lse;
}

// ===================== fallback: round-2 CSR pipeline ========================

__global__ void k_zero(int* cnt, int n) {
    int i = blockIdx.x * blockDim.x + threadIdx.x;
    if (i < n) cnt[i] = 0;
}

__global__ void k_count_pos(const int* __restrict__ col, int e,
                            int* __restrict__ cnt, int* __restrict__ pos) {
    int i = blockIdx.x * blockDim.x + threadIdx.x;
    if (i < e) pos[i] = atomicAdd(&cnt[col[i]], 1);
}

__global__ void k_scan1(const int* __restrict__ cnt, int n,
                        int* __restrict__ excl, int* __restrict__ bsum) {
    __shared__ int s[256];
    int i = blockIdx.x * 256 + threadIdx.x;
    int v = (i < n) ? cnt[i] : 0;
    s[threadIdx.x] = v;
    __syncthreads();
    for (int off = 1; off < 256; off <<= 1) {
        int t = (threadIdx.x >= off) ? s[threadIdx.x - off] : 0;
        __syncthreads();
        s[threadIdx.x] += t;
        __syncthreads();
    }
    if (i < n) excl[i] = s[threadIdx.x] - v;
    if (threadIdx.x == 255) bsum[blockIdx.x] = s[255];
}

__global__ void k_scan2(int* __restrict__ bsum, int nb) {
    __shared__ int s[1024];
    int v = (threadIdx.x < nb) ? bsum[threadIdx.x] : 0;
    s[threadIdx.x] = v;
    __syncthreads();
    for (int off = 1; off < 1024; off <<= 1) {
        int t = (threadIdx.x >= off) ? s[threadIdx.x - off] : 0;
        __syncthreads();
        s[threadIdx.x] += t;
        __syncthreads();
    }
    if (threadIdx.x < nb) bsum[threadIdx.x] = s[threadIdx.x] - v;
}

__global__ void k_scan3(int* __restrict__ excl, const int* __restrict__ boff, int n) {
    int i = blockIdx.x * 256 + threadIdx.x;
    if (i < n) excl[i] += boff[blockIdx.x];
}

__global__ void k_place(const int* __restrict__ row, const int* __restrict__ col,
                        const int* __restrict__ pos, const int* __restrict__ ptr,
                        int e, int* __restrict__ csr) {
    int i = blockIdx.x * blockDim.x + threadIdx.x;
    if (i >= e) return;
    csr[ptr[col[i]] + pos[i]] = row[i];
}

__global__ void k_dinv_from_cnt(const int* __restrict__ cnt, float* __restrict__ dinv, int n) {
    int i = blockIdx.x * blockDim.x + threadIdx.x;
    if (i < n) dinv[i] = rsqrtf((float)(cnt[i] + 1));
}

// ============================== host launcher ================================

extern "C" void kernel_launch(void* const* d_in, const int* in_sizes, int n_in,
                              void* d_out, int out_size, void* d_ws, size_t ws_size,
                              hipStream_t stream) {
    const float* x  = (const float*)d_in[0];
    const int*   ei = (const int*)d_in[1];
    const float* W1 = (const float*)d_in[2];
    const float* b1 = (const float*)d_in[3];
    const float* W2 = (const float*)d_in[4];
    const float* b2 = (const float*)d_in[5];
    float* out = (float*)d_out;

    const int N = in_sizes[0] / 25;
    const int E = in_sizes[1] / 2;
    const int* row = ei;
    const int* col = ei + E;

    const int nbins = (N + NPB - 1) / NPB;
    const int gN = (N + THREADS - 1) / THREADS;
    const int gE = (E + THREADS - 1) / THREADS;

    size_t off = 0;
    auto take = [&](size_t bytes) { size_t o = off; off = (off + bytes + 255) & ~(size_t)255; return o; };
    size_t o_binCnt = take(MAX_BINS * sizeof(int));
    size_t o_binned = take((size_t)nbins * CAPE * sizeof(int));
    size_t o_csr    = take((size_t)nbins * CAPE * sizeof(int));
    size_t o_ptr    = take((size_t)N * sizeof(int));
    size_t o_cnt    = take((size_t)N * sizeof(int));
    size_t o_dinv   = take((size_t)N * sizeof(float));
    size_t o_z1h    = take((size_t)N * 16 * sizeof(__half));
    size_t o_z2h    = take((size_t)N * sizeof(__half2));
    size_t need_v9 = off;

    double mu = (double)E / (double)nbins;
    bool cap_ok = (mu + 8.0 * sqrt(mu)) < (double)CAPE;
    const int per = (((E + BIN_BLOCKS - 1) / BIN_BLOCKS) + 3) & ~3;
    size_t dynLds = (size_t)per * 9 + 64;  // sbuf + sbuf2 (4B each) + sbin (1B)
    bool lds_ok = dynLds <= 60 * 1024;
    bool use_v9 = (nbins <= MAX_BINS) && (ws_size >= need_v9) &&
                  (N <= NPB * MAX_BINS) && (N < (1 << 17)) && cap_ok && lds_ok;

    char* wsb = (char*)d_ws;
    if (use_v9) {
        int*     binCnt = (int*)(wsb + o_binCnt);
        int*     binned = (int*)(wsb + o_binned);
        int*     csr    = (int*)(wsb + o_csr);
        int*     ptr    = (int*)(wsb + o_ptr);
        int*     cnt    = (int*)(wsb + o_cnt);
        float*   dinv   = (float*)(wsb + o_dinv);
        __half*  z1h    = (__half*)(wsb + o_z1h);
        __half2* z2h    = (__half2*)(wsb + o_z2h);

        hipMemsetAsync(binCnt, 0, MAX_BINS * sizeof(int), stream);
        k_bin<<<BIN_BLOCKS, 256, dynLds, stream>>>(row, col, E, binCnt, binned);
        k_sort<<<nbins, 1024, 0, stream>>>(binned, binCnt, csr, ptr, cnt, dinv, N);
        k_xform1<<<gN, 256, 0, stream>>>(x, W1, dinv, z1h, N);
        k_gather1<<<(N + 31) / 32, 256, 0, stream>>>(ptr, cnt, csr, z1h, dinv, b1, W2, z2h, N);
        k_gather2<<<gN, THREADS, 0, stream>>>(ptr, cnt, csr, z2h, dinv, b2, out, N);
    } else {
        char* w = wsb;
        int*     cnt  = (int*)w;     w += (size_t)N * sizeof(int);
        int*     ptr  = (int*)w;     w += (size_t)N * sizeof(int);
        int*     pos  = (int*)w;     w += (size_t)E * sizeof(int);
        int*     csr  = (int*)w;     w += (size_t)E * sizeof(int);
        int*     bsum = (int*)w;     w += (size_t)1024 * sizeof(int);
        float*   dinv = (float*)w;   w += (size_t)N * sizeof(float);
        __half*  z1h  = (__half*)w;  w += (size_t)N * 16 * sizeof(__half);
        __half2* z2h  = (__half2*)w; w += (size_t)N * sizeof(__half2);
        const int NB = (N + 255) / 256;

        k_zero<<<gN, THREADS, 0, stream>>>(cnt, N);
        k_count_pos<<<gE, THREADS, 0, stream>>>(col, E, cnt, pos);
        k_scan1<<<NB, 256, 0, stream>>>(cnt, N, ptr, bsum);
        k_scan2<<<1, 1024, 0, stream>>>(bsum, NB);
        k_scan3<<<NB, 256, 0, stream>>>(ptr, bsum, N);
        k_place<<<gE, THREADS, 0, stream>>>(row, col, pos, ptr, E, csr);
        k_dinv_from_cnt<<<gN, THREADS, 0, stream>>>(cnt, dinv, N);
        k_xform1<<<gN, 256, 0, stream>>>(x, W1, dinv, z1h, N);
        k_gather1<<<(N + 31) / 32, 256, 0, stream>>>(ptr, cnt, csr, z1h, dinv, b1, W2, z2h, N);
        k_gather2<<<gN, THREADS, 0, stream>>>(ptr, cnt, csr, z2h, dinv, b2, out, N);
    }
}